// Round 5
// baseline (443.045 us; speedup 1.0000x reference)
//
#include <hip/hip_runtime.h>
#include <math.h>

#define NN 20000
#define EE 100000
#define RR 4
#define HH 4
#define DD 64
#define FF 128
#define LL 2
#define NB 79  // scan blocks per relation: ceil(20000/256)

typedef __attribute__((ext_vector_type(8))) short bf16x8;
typedef __attribute__((ext_vector_type(4))) float f32x4;

__device__ __forceinline__ ushort f2bf(float f) {
  uint u = __float_as_uint(f);
  u += 0x7FFFu + ((u >> 16) & 1u);
  return (ushort)(u >> 16);
}
__device__ __forceinline__ float bf2f(ushort h) {
  return __uint_as_float((uint)h << 16);
}

// ---------------------------------------------------------------------------
// Encoder: x = feat@Wf + bf + cen@Wc + bc ; writes fp32 x and bf16 xbf
__global__ __launch_bounds__(256) void encoder_kernel(
    const float* __restrict__ feat, const float* __restrict__ bet,
    const float* __restrict__ clo, const float* __restrict__ Wf,
    const float* __restrict__ bf, const float* __restrict__ Wc,
    const float* __restrict__ bc, float* __restrict__ x,
    ushort* __restrict__ xbf) {
  __shared__ float fs[4][FF];
  const int t = threadIdx.x;
  const int n0 = blockIdx.x * 4;
  for (int idx = t; idx < 4 * FF; idx += 256) {
    const int rr = idx >> 7, cc = idx & 127;
    const int n = n0 + rr;
    fs[rr][cc] = (n < NN) ? feat[(size_t)n * FF + cc] : 0.f;
  }
  __syncthreads();
  const int g = t >> 6, d = t & 63;
  const int n = n0 + g;
  if (n >= NN) return;
  float acc = bf[d] + bc[d] + bet[n] * Wc[d] + clo[n] * Wc[DD + d];
#pragma unroll 8
  for (int f = 0; f < FF; ++f) acc = fmaf(fs[g][f], Wf[f * DD + d], acc);
  x[(size_t)n * DD + d] = acc;
  xbf[(size_t)n * DD + d] = f2bf(acc);
}

// ---------------------------------------------------------------------------
// Weight pre-pack: wqkvT [l][r][768][64] bf16 (B^T), bqkv [l][r][768] f32,
//                  wpT [l][64][1024] bf16 (B^T)
__global__ __launch_bounds__(256) void pack_kernel(
    const float* __restrict__ Wq, const float* __restrict__ bq,
    const float* __restrict__ Wk, const float* __restrict__ bk,
    const float* __restrict__ Wv, const float* __restrict__ bv,
    const float* __restrict__ Wp, ushort* __restrict__ wqkvT,
    float* __restrict__ bqkv, ushort* __restrict__ wpT) {
  const int idx = blockIdx.x * 256 + threadIdx.x;
  const int P1 = LL * RR * 768 * 64;  // 393216
  if (idx < P1) {
    const int lr = idx / 49152;
    const int rem = idx % 49152;
    const int n = rem >> 6, k = rem & 63;
    const int sel = n >> 8, col = n & 255;
    const float* W = (sel == 0) ? Wq : (sel == 1) ? Wk : Wv;
    wqkvT[(size_t)lr * 49152 + n * 64 + k] =
        f2bf(W[(size_t)lr * 64 * 256 + k * 256 + col]);
    if (k == 0) {
      const float* B = (sel == 0) ? bq : (sel == 1) ? bk : bv;
      bqkv[lr * 768 + n] = B[lr * 256 + col];
    }
  } else if (idx < P1 + LL * 64 * 1024) {
    const int idx2 = idx - P1;
    const int l = idx2 >> 16;
    const int rem = idx2 & 65535;
    const int n = rem & 63, k = rem >> 6;
    wpT[(size_t)l * 65536 + n * 1024 + k] =
        f2bf(Wp[(size_t)l * 65536 + k * 64 + n]);
  }
}

// ---------------------------------------------------------------------------
// CSR build
__global__ __launch_bounds__(256) void hist_kernel(
    const int* __restrict__ esrc, int* __restrict__ counts) {
  const int e = blockIdx.x * 256 + threadIdx.x;
  const int r = blockIdx.y;
  if (e < EE) atomicAdd(&counts[r * NN + esrc[(size_t)r * EE + e]], 1);
}

__global__ __launch_bounds__(256) void scanA_kernel(
    const int* __restrict__ counts, int* __restrict__ offs,
    int* __restrict__ bsum) {
  __shared__ int tmp[256];
  const int r = blockIdx.y, bx = blockIdx.x, t = threadIdx.x;
  const int i = bx * 256 + t;
  tmp[t] = (i < NN) ? counts[r * NN + i] : 0;
  __syncthreads();
#pragma unroll
  for (int s = 1; s < 256; s <<= 1) {
    const int add = (t >= s) ? tmp[t - s] : 0;
    __syncthreads();
    tmp[t] += add;
    __syncthreads();
  }
  if (i < NN) offs[r * (NN + 1) + i + 1] = tmp[t];
  if (t == 255) bsum[r * NB + bx] = tmp[255];
}

__global__ __launch_bounds__(128) void scanB_kernel(int* __restrict__ bsum) {
  __shared__ int tmp[128];
  const int r = blockIdx.x, t = threadIdx.x;
  tmp[t] = (t < NB) ? bsum[r * NB + t] : 0;
  __syncthreads();
#pragma unroll
  for (int s = 1; s < 128; s <<= 1) {
    const int add = (t >= s) ? tmp[t - s] : 0;
    __syncthreads();
    tmp[t] += add;
    __syncthreads();
  }
  if (t < NB) bsum[r * NB + t] = (t == 0) ? 0 : tmp[t - 1];
}

__global__ __launch_bounds__(256) void scanC_kernel(
    const int* __restrict__ bsum, int* __restrict__ offs) {
  const int r = blockIdx.y, bx = blockIdx.x, t = threadIdx.x;
  const int i = bx * 256 + t;
  if (i < NN) offs[r * (NN + 1) + i + 1] += bsum[r * NB + bx];
  if (i == 0) offs[r * (NN + 1)] = 0;
}

__global__ __launch_bounds__(256) void fill_kernel(
    const int* __restrict__ esrc, const int* __restrict__ etgt,
    const int* __restrict__ offs, int* __restrict__ cursor,
    int* __restrict__ csr) {
  const int e = blockIdx.x * 256 + threadIdx.x;
  const int r = blockIdx.y;
  if (e < EE) {
    const int s = esrc[(size_t)r * EE + e];
    const int pos = offs[r * (NN + 1) + s] + atomicAdd(&cursor[r * NN + s], 1);
    csr[(size_t)r * EE + pos] = etgt[(size_t)r * EE + e];
  }
}

// ---------------------------------------------------------------------------
// QKV GEMM: grid (313, 4) = (m-tile of 64 rows, relation). block 256 = 4 waves.
// Wave w computes rows m0+w*16..+15 x all 768 cols; A-fragments loaded ONCE.
// Output layout qkv4[r][n][768] bf16. Epilogue: per-wave LDS region (no
// barriers; intra-wave lgkmcnt ordering suffices) + 512B-contiguous stores.
__global__ __launch_bounds__(256) void qkv_gemm_kernel(
    const ushort* __restrict__ xbf, const ushort* __restrict__ wqkvT_l,
    const float* __restrict__ bqkv_l, ushort* __restrict__ qkv4) {
  __shared__ ushort cs[4][16][264];  // per-wave: 16 rows x 256 cols (+8 pad)
  const int t = threadIdx.x;
  const int w = t >> 6, l = t & 63;
  const int hi = l >> 4, lo = l & 15;
  const int m0 = blockIdx.x * 64;
  const int r = blockIdx.y;
  const ushort* wT = wqkvT_l + (size_t)r * 49152;
  const float* bias = bqkv_l + r * 768;
  const int row = min(m0 + w * 16 + lo, NN - 1);
  const ushort* arow = xbf + (size_t)row * 64 + hi * 8;
  const bf16x8 a0 = *(const bf16x8*)(arow);
  const bf16x8 a1 = *(const bf16x8*)(arow + 32);
  ushort* qkv_r = qkv4 + (size_t)r * NN * 768;
  for (int c = 0; c < 3; ++c) {  // col chunks of 256
    const int n0c = c * 256;
    f32x4 acc[16];
#pragma unroll
    for (int nt = 0; nt < 16; ++nt) {
      const ushort* brow = wT + (size_t)(n0c + nt * 16 + lo) * 64 + hi * 8;
      const bf16x8 b0 = *(const bf16x8*)(brow);
      const bf16x8 b1 = *(const bf16x8*)(brow + 32);
      f32x4 z = {0.f, 0.f, 0.f, 0.f};
      z = __builtin_amdgcn_mfma_f32_16x16x32_bf16(a0, b0, z, 0, 0, 0);
      z = __builtin_amdgcn_mfma_f32_16x16x32_bf16(a1, b1, z, 0, 0, 0);
      acc[nt] = z;
    }
    // stage to this wave's LDS region (C-frag: col=lane&15, row=hi*4+i)
#pragma unroll
    for (int nt = 0; nt < 16; ++nt) {
#pragma unroll
      for (int i = 0; i < 4; ++i) {
        cs[w][hi * 4 + i][nt * 16 + lo] =
            f2bf(acc[nt][i] + bias[n0c + nt * 16 + lo]);
      }
    }
    // coalesced store: 16 rows x 512B (32 lanes cover one row's 32x16B pieces)
#pragma unroll
    for (int p = 0; p < 8; ++p) {
      const int idx = p * 64 + l;
      const int rr = idx >> 5;   // 0..15
      const int pc = idx & 31;   // 16B piece within row
      const int gm = m0 + w * 16 + rr;
      if (gm < NN) {
        *(uint4*)(qkv_r + (size_t)gm * 768 + n0c + pc * 8) =
            *(const uint4*)&cs[w][rr][pc * 8];
      }
    }
  }
}

// ---------------------------------------------------------------------------
// Attention, ALL relations in one dispatch: grid (ceil(N/4), 4), by = relation.
// One wave per node; lane l -> head h=l>>4, elem-offset 4*l (==h*64+(l&15)*4).
// qkv4[r][n][768]: [q(256) | k(256) | v(256)] bf16 per (r,n).
// 4 independent online-softmax streams, merged at the end.
__global__ __launch_bounds__(256) void attn_kernel(
    const ushort* __restrict__ qkv4, const int* __restrict__ offs4,
    const int* __restrict__ csr4, const float* __restrict__ nsi,
    const float* __restrict__ sw_l, ushort* __restrict__ attr) {
  const int t = threadIdx.x;
  const int w = t >> 6, l = t & 63;
  const int n = blockIdx.x * 4 + w;
  if (n >= NN) return;
  const int r = blockIdx.y;
  const int* offs = offs4 + r * (NN + 1);
  const int* csr = csr4 + (size_t)r * EE;
  const int h = l >> 4;
  const int off = l * 4;
  const ushort* qkv_r = qkv4 + (size_t)r * NN * 768;
  const ushort4 qu = *(const ushort4*)(qkv_r + (size_t)n * 768 + off);
  const float q0 = bf2f(qu.x), q1 = bf2f(qu.y), q2 = bf2f(qu.z),
              q3 = bf2f(qu.w);
  const float c = 0.125f * nsi[n] * sw_l[h * RR + r];
  const int s0 = offs[n], e0 = offs[n + 1];
  float m[4], den[4], o0[4], o1[4], o2[4], o3[4];
#pragma unroll
  for (int s = 0; s < 4; ++s) {
    m[s] = -INFINITY;
    den[s] = 0.f;
    o0[s] = 0.f;
    o1[s] = 0.f;
    o2[s] = 0.f;
    o3[s] = 0.f;
  }
  int i = s0;
  for (; i + 3 < e0; i += 4) {
    ushort4 ku[4], vu[4];
#pragma unroll
    for (int s = 0; s < 4; ++s) {
      const int tg = csr[i + s];
      const ushort* p = qkv_r + (size_t)tg * 768 + 256 + off;
      ku[s] = *(const ushort4*)(p);
      vu[s] = *(const ushort4*)(p + 256);
    }
    float dot[4];
#pragma unroll
    for (int s = 0; s < 4; ++s) {
      float d = q0 * bf2f(ku[s].x);
      d = fmaf(q1, bf2f(ku[s].y), d);
      d = fmaf(q2, bf2f(ku[s].z), d);
      d = fmaf(q3, bf2f(ku[s].w), d);
      dot[s] = d;
    }
#pragma unroll
    for (int d = 1; d < 16; d <<= 1) {
#pragma unroll
      for (int s = 0; s < 4; ++s) dot[s] += __shfl_xor(dot[s], d);
    }
#pragma unroll
    for (int s = 0; s < 4; ++s) {
      const float sc = dot[s] * c;
      const float mn = fmaxf(m[s], sc);
      const float esc = __expf(m[s] - mn);
      const float ew = __expf(sc - mn);
      den[s] = den[s] * esc + ew;
      o0[s] = fmaf(ew, bf2f(vu[s].x), o0[s] * esc);
      o1[s] = fmaf(ew, bf2f(vu[s].y), o1[s] * esc);
      o2[s] = fmaf(ew, bf2f(vu[s].z), o2[s] * esc);
      o3[s] = fmaf(ew, bf2f(vu[s].w), o3[s] * esc);
      m[s] = mn;
    }
  }
  for (; i < e0; ++i) {  // tail -> stream 0
    const int tg = csr[i];
    const ushort* p = qkv_r + (size_t)tg * 768 + 256 + off;
    const ushort4 ku = *(const ushort4*)(p);
    const ushort4 vu = *(const ushort4*)(p + 256);
    float d = q0 * bf2f(ku.x);
    d = fmaf(q1, bf2f(ku.y), d);
    d = fmaf(q2, bf2f(ku.z), d);
    d = fmaf(q3, bf2f(ku.w), d);
#pragma unroll
    for (int dd = 1; dd < 16; dd <<= 1) d += __shfl_xor(d, dd);
    const float sc = d * c;
    const float mn = fmaxf(m[0], sc);
    const float esc = __expf(m[0] - mn);
    const float ew = __expf(sc - mn);
    den[0] = den[0] * esc + ew;
    o0[0] = fmaf(ew, bf2f(vu.x), o0[0] * esc);
    o1[0] = fmaf(ew, bf2f(vu.y), o1[0] * esc);
    o2[0] = fmaf(ew, bf2f(vu.z), o2[0] * esc);
    o3[0] = fmaf(ew, bf2f(vu.w), o3[0] * esc);
    m[0] = mn;
  }
  // merge streams (guard empty streams: exp(-inf - -inf) would be NaN)
  float M = fmaxf(fmaxf(m[0], m[1]), fmaxf(m[2], m[3]));
  float D = 0.f, O0 = 0.f, O1 = 0.f, O2 = 0.f, O3 = 0.f;
#pragma unroll
  for (int s = 0; s < 4; ++s) {
    const float e = (m[s] > -INFINITY) ? __expf(m[s] - M) : 0.f;
    D = fmaf(den[s], e, D);
    O0 = fmaf(o0[s], e, O0);
    O1 = fmaf(o1[s], e, O1);
    O2 = fmaf(o2[s], e, O2);
    O3 = fmaf(o3[s], e, O3);
  }
  const float inv = 1.f / (D + 1e-10f);
  ushort4 ou;
  ou.x = f2bf(O0 * inv);
  ou.y = f2bf(O1 * inv);
  ou.z = f2bf(O2 * inv);
  ou.w = f2bf(O3 * inv);
  *(ushort4*)(attr + (size_t)n * 1024 + r * 256 + off) = ou;
}

// ---------------------------------------------------------------------------
// Projection (K=1024) + bias + residual + LayerNorm, fused.
// grid (N/16 = 1250), block 256 = 4 waves; each wave owns K-slice of 256;
// f32 partial reduce through LDS; wave 0 does the LN epilogue.
__global__ __launch_bounds__(256) void proj_ln_kernel(
    const ushort* __restrict__ attr, const ushort* __restrict__ wpT,
    const float* __restrict__ xin, const float* __restrict__ bp,
    const float* __restrict__ g, const float* __restrict__ b,
    float* __restrict__ xout, ushort* __restrict__ xbf_out) {
  __shared__ float red[4][64][20];  // [wave][lane][nt*4+i], pad to 80B stride
  const int t = threadIdx.x;
  const int w = t >> 6, l = t & 63;
  const int hi = l >> 4, lo = l & 15;
  const int m0 = blockIdx.x * 16;
  const ushort* arow = attr + (size_t)(m0 + lo) * 1024 + w * 256 + hi * 8;
  f32x4 acc[4] = {{0.f, 0.f, 0.f, 0.f},
                  {0.f, 0.f, 0.f, 0.f},
                  {0.f, 0.f, 0.f, 0.f},
                  {0.f, 0.f, 0.f, 0.f}};
#pragma unroll
  for (int ks = 0; ks < 8; ++ks) {
    const bf16x8 a = *(const bf16x8*)(arow + ks * 32);
#pragma unroll
    for (int nt = 0; nt < 4; ++nt) {
      const bf16x8 bb = *(const bf16x8*)(wpT + (size_t)(nt * 16 + lo) * 1024 +
                                         w * 256 + ks * 32 + hi * 8);
      acc[nt] = __builtin_amdgcn_mfma_f32_16x16x32_bf16(a, bb, acc[nt], 0, 0, 0);
    }
  }
#pragma unroll
  for (int nt = 0; nt < 4; ++nt) *(f32x4*)&red[w][l][nt * 4] = acc[nt];
  __syncthreads();
  if (w == 0) {
    f32x4 fin[4];
#pragma unroll
    for (int nt = 0; nt < 4; ++nt) {
      f32x4 s = *(const f32x4*)&red[0][l][nt * 4];
      s += *(const f32x4*)&red[1][l][nt * 4];
      s += *(const f32x4*)&red[2][l][nt * 4];
      s += *(const f32x4*)&red[3][l][nt * 4];
      fin[nt] = s;
    }
#pragma unroll
    for (int i = 0; i < 4; ++i) {
      const int gr = m0 + hi * 4 + i;
      float y[4];
      float s = 0.f, s2 = 0.f;
#pragma unroll
      for (int nt = 0; nt < 4; ++nt) {
        const int col = nt * 16 + lo;
        const float yv = fin[nt][i] + bp[col] + xin[(size_t)gr * 64 + col];
        y[nt] = yv;
        s += yv;
        s2 = fmaf(yv, yv, s2);
      }
#pragma unroll
      for (int d = 1; d < 16; d <<= 1) {
        s += __shfl_xor(s, d);
        s2 += __shfl_xor(s2, d);
      }
      const float mu = s * (1.f / 64.f);
      const float var = s2 * (1.f / 64.f) - mu * mu;
      const float rstd = rsqrtf(var + 1e-5f);
#pragma unroll
      for (int nt = 0; nt < 4; ++nt) {
        const int col = nt * 16 + lo;
        const float xo = (y[nt] - mu) * rstd * g[col] + b[col];
        xout[(size_t)gr * 64 + col] = xo;
        if (xbf_out) xbf_out[(size_t)gr * 64 + col] = f2bf(xo);
      }
    }
  }
}

// ---------------------------------------------------------------------------
extern "C" void kernel_launch(void* const* d_in, const int* in_sizes, int n_in,
                              void* d_out, int out_size, void* d_ws,
                              size_t ws_size, hipStream_t stream) {
  const float* feat = (const float*)d_in[1];
  const float* bet = (const float*)d_in[2];
  const float* clo = (const float*)d_in[3];
  const float* nsi = (const float*)d_in[4];
  const int* esrc = (const int*)d_in[5];
  const int* etgt = (const int*)d_in[6];
  const float* Wf = (const float*)d_in[7];
  const float* bf = (const float*)d_in[8];
  const float* Wc = (const float*)d_in[9];
  const float* bc = (const float*)d_in[10];
  const float* Wq = (const float*)d_in[11];
  const float* bq = (const float*)d_in[12];
  const float* Wk = (const float*)d_in[13];
  const float* bk = (const float*)d_in[14];
  const float* Wv = (const float*)d_in[15];
  const float* bv = (const float*)d_in[16];
  const float* Wp = (const float*)d_in[17];
  const float* bp = (const float*)d_in[18];
  const float* sw = (const float*)d_in[19];
  const float* lng = (const float*)d_in[20];
  const float* lnb = (const float*)d_in[21];
  float* out = (float*)d_out;

  char* base = (char*)d_ws;
  size_t off = 0;
  auto alloc = [&](size_t bytes) {
    void* p = base + off;
    off += (bytes + 255) & ~(size_t)255;
    return p;
  };
  float* xa = (float*)alloc((size_t)NN * DD * 4);           // 5.12 MB
  float* xb = (float*)alloc((size_t)NN * DD * 4);           // 5.12 MB
  ushort* xbf = (ushort*)alloc((size_t)NN * DD * 2);        // 2.56 MB
  ushort* qkv4 = (ushort*)alloc((size_t)NN * 3072 * 2);     // 122.88 MB
  ushort* attr = (ushort*)alloc((size_t)NN * 1024 * 2);     // 40.96 MB
  ushort* wqkvT = (ushort*)alloc((size_t)LL * RR * 768 * 64 * 2);
  float* bqkv = (float*)alloc((size_t)LL * RR * 768 * 4);
  ushort* wpT = (ushort*)alloc((size_t)LL * 64 * 1024 * 2);
  int* counts = (int*)alloc((size_t)RR * NN * 4);
  int* offsb = (int*)alloc((size_t)RR * (NN + 1) * 4);
  int* bsum = (int*)alloc((size_t)RR * NB * 4);
  int* csr = (int*)alloc((size_t)RR * EE * 4);
  (void)ws_size;

  // ---- CSR build ----
  hipMemsetAsync(counts, 0, (size_t)RR * NN * 4, stream);
  {
    dim3 gg((EE + 255) / 256, RR);
    hipLaunchKernelGGL(hist_kernel, gg, dim3(256), 0, stream, esrc, counts);
  }
  {
    dim3 gg(NB, RR);
    hipLaunchKernelGGL(scanA_kernel, gg, dim3(256), 0, stream, counts, offsb,
                       bsum);
    hipLaunchKernelGGL(scanB_kernel, dim3(RR), dim3(128), 0, stream, bsum);
    hipLaunchKernelGGL(scanC_kernel, gg, dim3(256), 0, stream, bsum, offsb);
  }
  hipMemsetAsync(counts, 0, (size_t)RR * NN * 4, stream);  // reuse as cursor
  {
    dim3 gg((EE + 255) / 256, RR);
    hipLaunchKernelGGL(fill_kernel, gg, dim3(256), 0, stream, esrc, etgt, offsb,
                       counts, csr);
  }

  // ---- weight pre-pack + encoder ----
  hipLaunchKernelGGL(pack_kernel, dim3(2048), dim3(256), 0, stream, Wq, bq, Wk,
                     bk, Wv, bv, Wp, wqkvT, bqkv, wpT);
  hipLaunchKernelGGL(encoder_kernel, dim3((NN + 3) / 4), dim3(256), 0, stream,
                     feat, bet, clo, Wf, bf, Wc, bc, xa, xbf);

  const int gm = (NN + 63) / 64;  // 313
  for (int l = 0; l < LL; ++l) {
    const float* xin = (l == 0) ? xa : xb;
    float* xout = (l == LL - 1) ? out : xb;
    ushort* xbf_next = (l == LL - 1) ? (ushort*)nullptr : xbf;
    hipLaunchKernelGGL(qkv_gemm_kernel, dim3(gm, RR), dim3(256), 0, stream, xbf,
                       wqkvT + (size_t)l * RR * 49152, bqkv + l * RR * 768,
                       qkv4);
    hipLaunchKernelGGL(attn_kernel, dim3((NN + 3) / 4, RR), dim3(256), 0,
                       stream, qkv4, offsb, csr, nsi, sw + l * HH * RR, attr);
    hipLaunchKernelGGL(proj_ln_kernel, dim3(NN / 16), dim3(256), 0, stream,
                       attr, wpT + (size_t)l * 65536, xin, bp + l * 64,
                       lng + l * 64, lnb + l * 64, xout, xbf_next);
  }
}

// Round 6
// 343.057 us; speedup vs baseline: 1.2915x; 1.2915x over previous
//
#include <hip/hip_runtime.h>
#include <math.h>

#define NN 20000
#define EE 100000
#define RR 4
#define HH 4
#define DD 64
#define FF 128
#define LL 2
#define NB 79  // scan blocks per relation: ceil(20000/256)

typedef __attribute__((ext_vector_type(8))) short bf16x8;
typedef __attribute__((ext_vector_type(4))) float f32x4;

__device__ __forceinline__ ushort f2bf(float f) {
  uint u = __float_as_uint(f);
  u += 0x7FFFu + ((u >> 16) & 1u);
  return (ushort)(u >> 16);
}
__device__ __forceinline__ float bf2f(ushort h) {
  return __uint_as_float((uint)h << 16);
}

// ---------------------------------------------------------------------------
// Encoder: x = feat@Wf + bf + cen@Wc + bc ; writes fp32 x and bf16 xbf
__global__ __launch_bounds__(256) void encoder_kernel(
    const float* __restrict__ feat, const float* __restrict__ bet,
    const float* __restrict__ clo, const float* __restrict__ Wf,
    const float* __restrict__ bf, const float* __restrict__ Wc,
    const float* __restrict__ bc, float* __restrict__ x,
    ushort* __restrict__ xbf) {
  __shared__ float fs[4][FF];
  const int t = threadIdx.x;
  const int n0 = blockIdx.x * 4;
  for (int idx = t; idx < 4 * FF; idx += 256) {
    const int rr = idx >> 7, cc = idx & 127;
    const int n = n0 + rr;
    fs[rr][cc] = (n < NN) ? feat[(size_t)n * FF + cc] : 0.f;
  }
  __syncthreads();
  const int g = t >> 6, d = t & 63;
  const int n = n0 + g;
  if (n >= NN) return;
  float acc = bf[d] + bc[d] + bet[n] * Wc[d] + clo[n] * Wc[DD + d];
#pragma unroll 8
  for (int f = 0; f < FF; ++f) acc = fmaf(fs[g][f], Wf[f * DD + d], acc);
  x[(size_t)n * DD + d] = acc;
  xbf[(size_t)n * DD + d] = f2bf(acc);
}

// ---------------------------------------------------------------------------
// Precompute fused weights (exact, fp32 accum):
//  mT[l][r][272][64] bf16: cols 0..255: M_h[i][j] = sum_d Wq[i][h64+d]Wk[j][h64+d]
//                          cols 256..259: walpha_h[i] = sum_d Wq[i][h64+d] bk[h64+d]
//                          cols 260..263: wbeta_h[i]  = sum_d Wk[i][h64+d] bq[h64+d]
//  gT[l][64][1024] bf16:  gT[j][r*256+h*64+v] = sum_d Wv[v][h64+d] Wp[r256+h64+d][j]
//  cvec[l][r][64] f32:    sum_idx bv[idx] Wp[r*256+idx][j]   (deg>0 const)
//  gam[l][r][h] f32:      bq_h . bk_h
__global__ __launch_bounds__(256) void prep_kernel(
    const float* __restrict__ Wq, const float* __restrict__ bq,
    const float* __restrict__ Wk, const float* __restrict__ bk,
    const float* __restrict__ Wv, const float* __restrict__ bv,
    const float* __restrict__ Wp, ushort* __restrict__ mT,
    ushort* __restrict__ gT, float* __restrict__ cvec,
    float* __restrict__ gam) {
  const int idx = blockIdx.x * 256 + threadIdx.x;
  const int R1 = LL * RR * 272 * 64;  // 139264
  const int R2 = LL * 64 * 1024;      // 131072
  if (idx < R1) {
    const int lr = idx / (272 * 64);
    const int rem = idx % (272 * 64);
    const int col = rem >> 6, i = rem & 63;
    const float* wq = Wq + (size_t)lr * 64 * 256;
    const float* wk = Wk + (size_t)lr * 64 * 256;
    float v = 0.f;
    if (col < 256) {
      const int h = col >> 6, j = col & 63;
      const float* qa = wq + (size_t)i * 256 + h * 64;
      const float* kb = wk + (size_t)j * 256 + h * 64;
#pragma unroll 8
      for (int d = 0; d < 64; ++d) v = fmaf(qa[d], kb[d], v);
    } else if (col < 260) {
      const int h = col - 256;
      const float* qa = wq + (size_t)i * 256 + h * 64;
      const float* bb = bk + lr * 256 + h * 64;
#pragma unroll 8
      for (int d = 0; d < 64; ++d) v = fmaf(qa[d], bb[d], v);
    } else if (col < 264) {
      const int h = col - 260;
      const float* ka = wk + (size_t)i * 256 + h * 64;
      const float* bb = bq + lr * 256 + h * 64;
#pragma unroll 8
      for (int d = 0; d < 64; ++d) v = fmaf(ka[d], bb[d], v);
    }
    mT[idx] = f2bf(v);
  } else if (idx < R1 + R2) {
    const int id = idx - R1;  // = l*65536 + j*1024 + k
    const int lj = id >> 10;
    const int k = id & 1023;
    const int l = lj >> 6, j = lj & 63;
    const int r = k >> 8, h = (k >> 6) & 3, v_ = k & 63;
    const float* wv = Wv + (size_t)(l * RR + r) * 64 * 256 + (size_t)v_ * 256 + h * 64;
    const float* wp = Wp + (size_t)l * 65536 + (size_t)(r * 256 + h * 64) * 64 + j;
    float s = 0.f;
#pragma unroll 8
    for (int d = 0; d < 64; ++d) s = fmaf(wv[d], wp[d * 64], s);
    gT[id] = f2bf(s);
  } else if (idx < R1 + R2 + 512) {
    const int id = idx - R1 - R2;  // = l*256 + r*64 + j
    const int l = id >> 8, rj = id & 255;
    const int r = rj >> 6, j = rj & 63;
    const float* bb = bv + (l * RR + r) * 256;
    const float* wp = Wp + (size_t)l * 65536 + (size_t)(r * 256) * 64 + j;
    float s = 0.f;
    for (int q2 = 0; q2 < 256; ++q2) s = fmaf(bb[q2], wp[q2 * 64], s);
    cvec[id] = s;
  } else if (idx < R1 + R2 + 512 + 32) {
    const int id = idx - R1 - R2 - 512;  // = l*16 + r*4 + h (lr*4+h)
    const int lr = id >> 2, h = id & 3;
    const float* a = bq + lr * 256 + h * 64;
    const float* b2 = bk + lr * 256 + h * 64;
    float s = 0.f;
    for (int d = 0; d < 64; ++d) s = fmaf(a[d], b2[d], s);
    gam[id] = s;
  }
}

// ---------------------------------------------------------------------------
// CSR build
__global__ __launch_bounds__(256) void hist_kernel(
    const int* __restrict__ esrc, int* __restrict__ counts) {
  const int e = blockIdx.x * 256 + threadIdx.x;
  const int r = blockIdx.y;
  if (e < EE) atomicAdd(&counts[r * NN + esrc[(size_t)r * EE + e]], 1);
}

__global__ __launch_bounds__(256) void scanA_kernel(
    const int* __restrict__ counts, int* __restrict__ offs,
    int* __restrict__ bsum) {
  __shared__ int tmp[256];
  const int r = blockIdx.y, bx = blockIdx.x, t = threadIdx.x;
  const int i = bx * 256 + t;
  tmp[t] = (i < NN) ? counts[r * NN + i] : 0;
  __syncthreads();
#pragma unroll
  for (int s = 1; s < 256; s <<= 1) {
    const int add = (t >= s) ? tmp[t - s] : 0;
    __syncthreads();
    tmp[t] += add;
    __syncthreads();
  }
  if (i < NN) offs[r * (NN + 1) + i + 1] = tmp[t];
  if (t == 255) bsum[r * NB + bx] = tmp[255];
}

__global__ __launch_bounds__(128) void scanB_kernel(int* __restrict__ bsum) {
  __shared__ int tmp[128];
  const int r = blockIdx.x, t = threadIdx.x;
  tmp[t] = (t < NB) ? bsum[r * NB + t] : 0;
  __syncthreads();
#pragma unroll
  for (int s = 1; s < 128; s <<= 1) {
    const int add = (t >= s) ? tmp[t - s] : 0;
    __syncthreads();
    tmp[t] += add;
    __syncthreads();
  }
  if (t < NB) bsum[r * NB + t] = (t == 0) ? 0 : tmp[t - 1];
}

__global__ __launch_bounds__(256) void scanC_kernel(
    const int* __restrict__ bsum, int* __restrict__ offs) {
  const int r = blockIdx.y, bx = blockIdx.x, t = threadIdx.x;
  const int i = bx * 256 + t;
  if (i < NN) offs[r * (NN + 1) + i + 1] += bsum[r * NB + bx];
  if (i == 0) offs[r * (NN + 1)] = 0;
}

__global__ __launch_bounds__(256) void fill_kernel(
    const int* __restrict__ esrc, const int* __restrict__ etgt,
    const int* __restrict__ offs, int* __restrict__ cursor,
    int* __restrict__ csr) {
  const int e = blockIdx.x * 256 + threadIdx.x;
  const int r = blockIdx.y;
  if (e < EE) {
    const int s = esrc[(size_t)r * EE + e];
    const int pos = offs[r * (NN + 1) + s] + atomicAdd(&cursor[r * NN + s], 1);
    csr[(size_t)r * EE + pos] = etgt[(size_t)r * EE + e];
  }
}

// ---------------------------------------------------------------------------
// Y-GEMM (R4 structure): grid (313, 20): r = by/5, tile = by%5.
// tile<4: Y[r][n][256] cols tile*64..+63. tile==4: ab[r][n][8] (alpha|beta).
__global__ __launch_bounds__(256) void ygemm_kernel(
    const ushort* __restrict__ xbf, const ushort* __restrict__ mT_l,
    ushort* __restrict__ Y, ushort* __restrict__ ab) {
  const int t = threadIdx.x;
  const int w = t >> 6, l = t & 63;
  const int hi = l >> 4, lo = l & 15;
  const int m0 = blockIdx.x * 64;
  const int r = blockIdx.y / 5;
  const int tile = blockIdx.y % 5;
  const ushort* wT = mT_l + (size_t)r * 17408;  // [272][64]
  const int row = min(m0 + w * 16 + lo, NN - 1);
  const ushort* arow = xbf + (size_t)row * 64 + hi * 8;
  const bf16x8 a0 = *(const bf16x8*)(arow);
  const bf16x8 a1 = *(const bf16x8*)(arow + 32);
  if (tile < 4) {
    const int n0 = tile * 64;
    f32x4 acc[4];
#pragma unroll
    for (int nt = 0; nt < 4; ++nt) {
      const ushort* brow = wT + (size_t)(n0 + nt * 16 + lo) * 64 + hi * 8;
      const bf16x8 b0 = *(const bf16x8*)(brow);
      const bf16x8 b1 = *(const bf16x8*)(brow + 32);
      f32x4 z = {0.f, 0.f, 0.f, 0.f};
      z = __builtin_amdgcn_mfma_f32_16x16x32_bf16(a0, b0, z, 0, 0, 0);
      z = __builtin_amdgcn_mfma_f32_16x16x32_bf16(a1, b1, z, 0, 0, 0);
      acc[nt] = z;
    }
    __shared__ ushort cs[64][72];
#pragma unroll
    for (int nt = 0; nt < 4; ++nt) {
#pragma unroll
      for (int i = 0; i < 4; ++i) {
        cs[w * 16 + hi * 4 + i][nt * 16 + lo] = f2bf(acc[nt][i]);
      }
    }
    __syncthreads();
    const int rr = t >> 2, c0 = (t & 3) * 16;
    const int gm = m0 + rr;
    if (gm < NN) {
      const uint4 v0 = *(const uint4*)&cs[rr][c0];
      const uint4 v1 = *(const uint4*)&cs[rr][c0 + 8];
      ushort* dst = Y + ((size_t)r * NN + gm) * 256 + n0 + c0;
      *(uint4*)(dst) = v0;
      *(uint4*)(dst + 8) = v1;
    }
  } else {
    // alpha/beta tile: cols 256..271 of mT (8 real)
    const ushort* brow = wT + (size_t)(256 + lo) * 64 + hi * 8;
    const bf16x8 b0 = *(const bf16x8*)(brow);
    const bf16x8 b1 = *(const bf16x8*)(brow + 32);
    f32x4 z = {0.f, 0.f, 0.f, 0.f};
    z = __builtin_amdgcn_mfma_f32_16x16x32_bf16(a0, b0, z, 0, 0, 0);
    z = __builtin_amdgcn_mfma_f32_16x16x32_bf16(a1, b1, z, 0, 0, 0);
#pragma unroll
    for (int i = 0; i < 4; ++i) {
      const int gm = m0 + w * 16 + hi * 4 + i;
      if (gm < NN && lo < 8) {
        ab[((size_t)r * NN + gm) * 8 + lo] = f2bf(z[i]);
      }
    }
  }
}

// ---------------------------------------------------------------------------
// Attention: one block per node; wave = relation; 16 lanes per head x 4 dims.
// score = (Y[src].x[tgt] + alpha[src] + beta[tgt] + gamma) * 0.125*nsi*sw.
// agg = sum attn * x[tgt]  (V/proj folded later via gT). x gathers L2-resident.
__global__ __launch_bounds__(256) void attn_kernel(
    const ushort* __restrict__ xbf, const ushort* __restrict__ Y,
    const ushort* __restrict__ ab, const int* __restrict__ offs4,
    const int* __restrict__ csr4, const float* __restrict__ nsi,
    const float* __restrict__ sw_l, const float* __restrict__ gam_l,
    ushort* __restrict__ attr) {
  const int n = blockIdx.x;
  const int t = threadIdx.x;
  const int r = t >> 6, l = t & 63;
  const int h = l >> 4, lo = l & 15;
  const int* offs = offs4 + r * (NN + 1);
  const int* csr = csr4 + (size_t)r * EE;
  const ushort4 yu = *(const ushort4*)(Y + ((size_t)r * NN + n) * 256 + l * 4);
  const float y0 = bf2f(yu.x), y1 = bf2f(yu.y), y2 = bf2f(yu.z),
              y3 = bf2f(yu.w);
  const float alpha = bf2f(ab[((size_t)r * NN + n) * 8 + h]) + gam_l[r * 4 + h];
  const float c = 0.125f * nsi[n] * sw_l[h * RR + r];
  const int s0 = offs[n], e0 = offs[n + 1];
  float m[4], den[4], o0[4], o1[4], o2[4], o3[4];
#pragma unroll
  for (int s = 0; s < 4; ++s) {
    m[s] = -INFINITY;
    den[s] = 0.f;
    o0[s] = 0.f;
    o1[s] = 0.f;
    o2[s] = 0.f;
    o3[s] = 0.f;
  }
  int i = s0;
  for (; i + 3 < e0; i += 4) {
    ushort4 xu[4];
    float be[4];
#pragma unroll
    for (int s = 0; s < 4; ++s) {
      const int tg = csr[i + s];
      xu[s] = *(const ushort4*)(xbf + (size_t)tg * 64 + lo * 4);
      be[s] = bf2f(ab[((size_t)r * NN + tg) * 8 + 4 + h]);
    }
    float dot[4];
#pragma unroll
    for (int s = 0; s < 4; ++s) {
      float d = y0 * bf2f(xu[s].x);
      d = fmaf(y1, bf2f(xu[s].y), d);
      d = fmaf(y2, bf2f(xu[s].z), d);
      d = fmaf(y3, bf2f(xu[s].w), d);
      dot[s] = d;
    }
#pragma unroll
    for (int d = 1; d < 16; d <<= 1) {
#pragma unroll
      for (int s = 0; s < 4; ++s) dot[s] += __shfl_xor(dot[s], d);
    }
#pragma unroll
    for (int s = 0; s < 4; ++s) {
      const float sc = (dot[s] + alpha + be[s]) * c;
      const float mn = fmaxf(m[s], sc);
      const float esc = __expf(m[s] - mn);
      const float ew = __expf(sc - mn);
      den[s] = den[s] * esc + ew;
      o0[s] = fmaf(ew, bf2f(xu[s].x), o0[s] * esc);
      o1[s] = fmaf(ew, bf2f(xu[s].y), o1[s] * esc);
      o2[s] = fmaf(ew, bf2f(xu[s].z), o2[s] * esc);
      o3[s] = fmaf(ew, bf2f(xu[s].w), o3[s] * esc);
      m[s] = mn;
    }
  }
  for (; i < e0; ++i) {  // tail -> stream 0
    const int tg = csr[i];
    const ushort4 xu = *(const ushort4*)(xbf + (size_t)tg * 64 + lo * 4);
    const float be = bf2f(ab[((size_t)r * NN + tg) * 8 + 4 + h]);
    float d = y0 * bf2f(xu.x);
    d = fmaf(y1, bf2f(xu.y), d);
    d = fmaf(y2, bf2f(xu.z), d);
    d = fmaf(y3, bf2f(xu.w), d);
#pragma unroll
    for (int dd = 1; dd < 16; dd <<= 1) d += __shfl_xor(d, dd);
    const float sc = (d + alpha + be) * c;
    const float mn = fmaxf(m[0], sc);
    const float esc = __expf(m[0] - mn);
    const float ew = __expf(sc - mn);
    den[0] = den[0] * esc + ew;
    o0[0] = fmaf(ew, bf2f(xu.x), o0[0] * esc);
    o1[0] = fmaf(ew, bf2f(xu.y), o1[0] * esc);
    o2[0] = fmaf(ew, bf2f(xu.z), o2[0] * esc);
    o3[0] = fmaf(ew, bf2f(xu.w), o3[0] * esc);
    m[0] = mn;
  }
  // merge streams (guard empty streams)
  float M = fmaxf(fmaxf(m[0], m[1]), fmaxf(m[2], m[3]));
  float D = 0.f, O0 = 0.f, O1 = 0.f, O2 = 0.f, O3 = 0.f;
#pragma unroll
  for (int s = 0; s < 4; ++s) {
    const float e = (m[s] > -INFINITY) ? __expf(m[s] - M) : 0.f;
    D = fmaf(den[s], e, D);
    O0 = fmaf(o0[s], e, O0);
    O1 = fmaf(o1[s], e, O1);
    O2 = fmaf(o2[s], e, O2);
    O3 = fmaf(o3[s], e, O3);
  }
  const float inv = 1.f / (D + 1e-10f);
  ushort4 ou;
  ou.x = f2bf(O0 * inv);
  ou.y = f2bf(O1 * inv);
  ou.z = f2bf(O2 * inv);
  ou.w = f2bf(O3 * inv);
  *(ushort4*)(attr + (size_t)n * 1024 + r * 256 + l * 4) = ou;
}

// ---------------------------------------------------------------------------
// Projection via fused G (K=1024) + masked bv-consts + bias + residual + LN.
// grid (N/16), block 256 = 4 waves each own a 256-K-slice; LDS reduce; wave 0
// does the epilogue.
__global__ __launch_bounds__(256) void proj_ln_kernel(
    const ushort* __restrict__ attr, const ushort* __restrict__ gT,
    const float* __restrict__ xin, const float* __restrict__ bp,
    const float* __restrict__ g, const float* __restrict__ b,
    const int* __restrict__ offs4, const float* __restrict__ cvec_l,
    float* __restrict__ xout, ushort* __restrict__ xbf_out) {
  __shared__ float red[4][64][20];
  const int t = threadIdx.x;
  const int w = t >> 6, l = t & 63;
  const int hi = l >> 4, lo = l & 15;
  const int m0 = blockIdx.x * 16;
  const ushort* arow = attr + (size_t)(m0 + lo) * 1024 + w * 256 + hi * 8;
  f32x4 acc[4] = {{0.f, 0.f, 0.f, 0.f},
                  {0.f, 0.f, 0.f, 0.f},
                  {0.f, 0.f, 0.f, 0.f},
                  {0.f, 0.f, 0.f, 0.f}};
#pragma unroll
  for (int ks = 0; ks < 8; ++ks) {
    const bf16x8 a = *(const bf16x8*)(arow + ks * 32);
#pragma unroll
    for (int nt = 0; nt < 4; ++nt) {
      const bf16x8 bb = *(const bf16x8*)(gT + (size_t)(nt * 16 + lo) * 1024 +
                                         w * 256 + ks * 32 + hi * 8);
      acc[nt] = __builtin_amdgcn_mfma_f32_16x16x32_bf16(a, bb, acc[nt], 0, 0, 0);
    }
  }
#pragma unroll
  for (int nt = 0; nt < 4; ++nt) *(f32x4*)&red[w][l][nt * 4] = acc[nt];
  __syncthreads();
  if (w == 0) {
    f32x4 fin[4];
#pragma unroll
    for (int nt = 0; nt < 4; ++nt) {
      f32x4 s = *(const f32x4*)&red[0][l][nt * 4];
      s += *(const f32x4*)&red[1][l][nt * 4];
      s += *(const f32x4*)&red[2][l][nt * 4];
      s += *(const f32x4*)&red[3][l][nt * 4];
      fin[nt] = s;
    }
#pragma unroll
    for (int i = 0; i < 4; ++i) {
      const int gr = m0 + hi * 4 + i;
      float fl[4];
#pragma unroll
      for (int r = 0; r < 4; ++r) {
        fl[r] = (offs4[r * (NN + 1) + gr + 1] > offs4[r * (NN + 1) + gr])
                    ? 1.f
                    : 0.f;
      }
      float y[4];
      float s = 0.f, s2 = 0.f;
#pragma unroll
      for (int nt = 0; nt < 4; ++nt) {
        const int col = nt * 16 + lo;
        float extra = fl[0] * cvec_l[col] + fl[1] * cvec_l[64 + col] +
                      fl[2] * cvec_l[128 + col] + fl[3] * cvec_l[192 + col];
        const float yv =
            fin[nt][i] + bp[col] + extra + xin[(size_t)gr * 64 + col];
        y[nt] = yv;
        s += yv;
        s2 = fmaf(yv, yv, s2);
      }
#pragma unroll
      for (int d = 1; d < 16; d <<= 1) {
        s += __shfl_xor(s, d);
        s2 += __shfl_xor(s2, d);
      }
      const float mu = s * (1.f / 64.f);
      const float var = s2 * (1.f / 64.f) - mu * mu;
      const float rstd = rsqrtf(var + 1e-5f);
#pragma unroll
      for (int nt = 0; nt < 4; ++nt) {
        const int col = nt * 16 + lo;
        const float xo = (y[nt] - mu) * rstd * g[col] + b[col];
        xout[(size_t)gr * 64 + col] = xo;
        if (xbf_out) xbf_out[(size_t)gr * 64 + col] = f2bf(xo);
      }
    }
  }
}

// ---------------------------------------------------------------------------
extern "C" void kernel_launch(void* const* d_in, const int* in_sizes, int n_in,
                              void* d_out, int out_size, void* d_ws,
                              size_t ws_size, hipStream_t stream) {
  const float* feat = (const float*)d_in[1];
  const float* bet = (const float*)d_in[2];
  const float* clo = (const float*)d_in[3];
  const float* nsi = (const float*)d_in[4];
  const int* esrc = (const int*)d_in[5];
  const int* etgt = (const int*)d_in[6];
  const float* Wf = (const float*)d_in[7];
  const float* bf = (const float*)d_in[8];
  const float* Wc = (const float*)d_in[9];
  const float* bc = (const float*)d_in[10];
  const float* Wq = (const float*)d_in[11];
  const float* bq = (const float*)d_in[12];
  const float* Wk = (const float*)d_in[13];
  const float* bk = (const float*)d_in[14];
  const float* Wv = (const float*)d_in[15];
  const float* bv = (const float*)d_in[16];
  const float* Wp = (const float*)d_in[17];
  const float* bp = (const float*)d_in[18];
  const float* sw = (const float*)d_in[19];
  const float* lng = (const float*)d_in[20];
  const float* lnb = (const float*)d_in[21];
  float* out = (float*)d_out;

  char* base = (char*)d_ws;
  size_t off = 0;
  auto alloc = [&](size_t bytes) {
    void* p = base + off;
    off += (bytes + 255) & ~(size_t)255;
    return p;
  };
  float* xa = (float*)alloc((size_t)NN * DD * 4);        // 5.12 MB
  float* xb = (float*)alloc((size_t)NN * DD * 4);        // 5.12 MB
  ushort* xbf = (ushort*)alloc((size_t)NN * DD * 2);     // 2.56 MB
  ushort* Yb = (ushort*)alloc((size_t)RR * NN * 256 * 2);  // 40.96 MB
  ushort* ab = (ushort*)alloc((size_t)RR * NN * 8 * 2);    // 1.28 MB
  ushort* attr = (ushort*)alloc((size_t)NN * 1024 * 2);    // 40.96 MB
  ushort* mT = (ushort*)alloc((size_t)LL * RR * 272 * 64 * 2);  // 557 KB
  ushort* gT = (ushort*)alloc((size_t)LL * 64 * 1024 * 2);      // 262 KB
  float* cvec = (float*)alloc((size_t)LL * RR * 64 * 4);        // 2 KB
  float* gam = (float*)alloc((size_t)LL * RR * HH * 4);         // 128 B
  int* counts = (int*)alloc((size_t)RR * NN * 4);
  int* offsb = (int*)alloc((size_t)RR * (NN + 1) * 4);
  int* bsum = (int*)alloc((size_t)RR * NB * 4);
  int* csr = (int*)alloc((size_t)RR * EE * 4);
  (void)ws_size;

  // ---- CSR build ----
  hipMemsetAsync(counts, 0, (size_t)RR * NN * 4, stream);
  {
    dim3 gg((EE + 255) / 256, RR);
    hipLaunchKernelGGL(hist_kernel, gg, dim3(256), 0, stream, esrc, counts);
  }
  {
    dim3 gg(NB, RR);
    hipLaunchKernelGGL(scanA_kernel, gg, dim3(256), 0, stream, counts, offsb,
                       bsum);
    hipLaunchKernelGGL(scanB_kernel, dim3(RR), dim3(128), 0, stream, bsum);
    hipLaunchKernelGGL(scanC_kernel, gg, dim3(256), 0, stream, bsum, offsb);
  }
  hipMemsetAsync(counts, 0, (size_t)RR * NN * 4, stream);  // reuse as cursor
  {
    dim3 gg((EE + 255) / 256, RR);
    hipLaunchKernelGGL(fill_kernel, gg, dim3(256), 0, stream, esrc, etgt, offsb,
                       counts, csr);
  }

  // ---- fused-weight precompute + encoder ----
  hipLaunchKernelGGL(prep_kernel, dim3(1059), dim3(256), 0, stream, Wq, bq, Wk,
                     bk, Wv, bv, Wp, mT, gT, cvec, gam);
  hipLaunchKernelGGL(encoder_kernel, dim3((NN + 3) / 4), dim3(256), 0, stream,
                     feat, bet, clo, Wf, bf, Wc, bc, xa, xbf);

  const int gm = (NN + 63) / 64;  // 313
  for (int l = 0; l < LL; ++l) {
    const float* xin = (l == 0) ? xa : xb;
    float* xout = (l == LL - 1) ? out : xb;
    ushort* xbf_next = (l == LL - 1) ? (ushort*)nullptr : xbf;
    hipLaunchKernelGGL(ygemm_kernel, dim3(gm, 20), dim3(256), 0, stream, xbf,
                       mT + (size_t)l * RR * 17408, Yb, ab);
    hipLaunchKernelGGL(attn_kernel, dim3(NN), dim3(256), 0, stream, xbf, Yb,
                       ab, offsb, csr, nsi, sw + l * HH * RR, gam + l * 16,
                       attr);
    hipLaunchKernelGGL(proj_ln_kernel, dim3(NN / 16), dim3(256), 0, stream,
                       attr, gT + (size_t)l * 65536, xin, bp + l * 64,
                       lng + l * 64, lnb + l * 64, offsb, cvec + l * 256, xout,
                       xbf_next);
  }
}

// Round 7
// 338.270 us; speedup vs baseline: 1.3097x; 1.0142x over previous
//
#include <hip/hip_runtime.h>
#include <math.h>

#define NN 20000
#define EE 100000
#define RR 4
#define HH 4
#define DD 64
#define FF 128
#define LL 2
#define NB 79  // scan blocks per relation: ceil(20000/256)

typedef __attribute__((ext_vector_type(8))) short bf16x8;
typedef __attribute__((ext_vector_type(4))) float f32x4;

__device__ __forceinline__ ushort f2bf(float f) {
  uint u = __float_as_uint(f);
  u += 0x7FFFu + ((u >> 16) & 1u);
  return (ushort)(u >> 16);
}
__device__ __forceinline__ float bf2f(ushort h) {
  return __uint_as_float((uint)h << 16);
}

// ---------------------------------------------------------------------------
// Encoder: x = feat@Wf + bf + cen@Wc + bc ; writes fp32 x and bf16 xbf
__global__ __launch_bounds__(256) void encoder_kernel(
    const float* __restrict__ feat, const float* __restrict__ bet,
    const float* __restrict__ clo, const float* __restrict__ Wf,
    const float* __restrict__ bf, const float* __restrict__ Wc,
    const float* __restrict__ bc, float* __restrict__ x,
    ushort* __restrict__ xbf) {
  __shared__ float fs[4][FF];
  const int t = threadIdx.x;
  const int n0 = blockIdx.x * 4;
  for (int idx = t; idx < 4 * FF; idx += 256) {
    const int rr = idx >> 7, cc = idx & 127;
    const int n = n0 + rr;
    fs[rr][cc] = (n < NN) ? feat[(size_t)n * FF + cc] : 0.f;
  }
  __syncthreads();
  const int g = t >> 6, d = t & 63;
  const int n = n0 + g;
  if (n >= NN) return;
  float acc = bf[d] + bc[d] + bet[n] * Wc[d] + clo[n] * Wc[DD + d];
#pragma unroll 8
  for (int f = 0; f < FF; ++f) acc = fmaf(fs[g][f], Wf[f * DD + d], acc);
  x[(size_t)n * DD + d] = acc;
  xbf[(size_t)n * DD + d] = f2bf(acc);
}

// ---------------------------------------------------------------------------
// Precompute fused weights (exact, fp32 accum):
//  mT[l][r][272][64] bf16: cols 0..255: M_h[i][j] = sum_d Wq[i][h64+d]Wk[j][h64+d]
//                          cols 256..259: walpha_h[i] = sum_d Wq[i][h64+d] bk[h64+d]
//                          cols 260..263: wbeta_h[i]  = sum_d Wk[i][h64+d] bq[h64+d]
//  gT[l][64][1024] bf16:  gT[j][r*256+h*64+v] = sum_d Wv[v][h64+d] Wp[r256+h64+d][j]
//  cvec[l][r][64] f32:    sum_idx bv[idx] Wp[r*256+idx][j]   (deg>0 const)
//  gam[l][r][h] f32:      bq_h . bk_h
__global__ __launch_bounds__(256) void prep_kernel(
    const float* __restrict__ Wq, const float* __restrict__ bq,
    const float* __restrict__ Wk, const float* __restrict__ bk,
    const float* __restrict__ Wv, const float* __restrict__ bv,
    const float* __restrict__ Wp, ushort* __restrict__ mT,
    ushort* __restrict__ gT, float* __restrict__ cvec,
    float* __restrict__ gam) {
  const int idx = blockIdx.x * 256 + threadIdx.x;
  const int R1 = LL * RR * 272 * 64;  // 139264
  const int R2 = LL * 64 * 1024;      // 131072
  if (idx < R1) {
    const int lr = idx / (272 * 64);
    const int rem = idx % (272 * 64);
    const int col = rem >> 6, i = rem & 63;
    const float* wq = Wq + (size_t)lr * 64 * 256;
    const float* wk = Wk + (size_t)lr * 64 * 256;
    float v = 0.f;
    if (col < 256) {
      const int h = col >> 6, j = col & 63;
      const float* qa = wq + (size_t)i * 256 + h * 64;
      const float* kb = wk + (size_t)j * 256 + h * 64;
#pragma unroll 8
      for (int d = 0; d < 64; ++d) v = fmaf(qa[d], kb[d], v);
    } else if (col < 260) {
      const int h = col - 256;
      const float* qa = wq + (size_t)i * 256 + h * 64;
      const float* bb = bk + lr * 256 + h * 64;
#pragma unroll 8
      for (int d = 0; d < 64; ++d) v = fmaf(qa[d], bb[d], v);
    } else if (col < 264) {
      const int h = col - 260;
      const float* ka = wk + (size_t)i * 256 + h * 64;
      const float* bb = bq + lr * 256 + h * 64;
#pragma unroll 8
      for (int d = 0; d < 64; ++d) v = fmaf(ka[d], bb[d], v);
    }
    mT[idx] = f2bf(v);
  } else if (idx < R1 + R2) {
    const int id = idx - R1;  // = l*65536 + j*1024 + k
    const int lj = id >> 10;
    const int k = id & 1023;
    const int l = lj >> 6, j = lj & 63;
    const int r = k >> 8, h = (k >> 6) & 3, v_ = k & 63;
    const float* wv = Wv + (size_t)(l * RR + r) * 64 * 256 + (size_t)v_ * 256 + h * 64;
    const float* wp = Wp + (size_t)l * 65536 + (size_t)(r * 256 + h * 64) * 64 + j;
    float s = 0.f;
#pragma unroll 8
    for (int d = 0; d < 64; ++d) s = fmaf(wv[d], wp[d * 64], s);
    gT[id] = f2bf(s);
  } else if (idx < R1 + R2 + 512) {
    const int id = idx - R1 - R2;  // = l*256 + r*64 + j
    const int l = id >> 8, rj = id & 255;
    const int r = rj >> 6, j = rj & 63;
    const float* bb = bv + (l * RR + r) * 256;
    const float* wp = Wp + (size_t)l * 65536 + (size_t)(r * 256) * 64 + j;
    float s = 0.f;
    for (int q2 = 0; q2 < 256; ++q2) s = fmaf(bb[q2], wp[q2 * 64], s);
    cvec[id] = s;
  } else if (idx < R1 + R2 + 512 + 32) {
    const int id = idx - R1 - R2 - 512;  // = l*16 + r*4 + h (lr*4+h)
    const int lr = id >> 2, h = id & 3;
    const float* a = bq + lr * 256 + h * 64;
    const float* b2 = bk + lr * 256 + h * 64;
    float s = 0.f;
    for (int d = 0; d < 64; ++d) s = fmaf(a[d], b2[d], s);
    gam[id] = s;
  }
}

// ---------------------------------------------------------------------------
// CSR build
__global__ __launch_bounds__(256) void hist_kernel(
    const int* __restrict__ esrc, int* __restrict__ counts) {
  const int e = blockIdx.x * 256 + threadIdx.x;
  const int r = blockIdx.y;
  if (e < EE) atomicAdd(&counts[r * NN + esrc[(size_t)r * EE + e]], 1);
}

__global__ __launch_bounds__(256) void scanA_kernel(
    const int* __restrict__ counts, int* __restrict__ offs,
    int* __restrict__ bsum) {
  __shared__ int tmp[256];
  const int r = blockIdx.y, bx = blockIdx.x, t = threadIdx.x;
  const int i = bx * 256 + t;
  tmp[t] = (i < NN) ? counts[r * NN + i] : 0;
  __syncthreads();
#pragma unroll
  for (int s = 1; s < 256; s <<= 1) {
    const int add = (t >= s) ? tmp[t - s] : 0;
    __syncthreads();
    tmp[t] += add;
    __syncthreads();
  }
  if (i < NN) offs[r * (NN + 1) + i + 1] = tmp[t];
  if (t == 255) bsum[r * NB + bx] = tmp[255];
}

__global__ __launch_bounds__(128) void scanB_kernel(int* __restrict__ bsum) {
  __shared__ int tmp[128];
  const int r = blockIdx.x, t = threadIdx.x;
  tmp[t] = (t < NB) ? bsum[r * NB + t] : 0;
  __syncthreads();
#pragma unroll
  for (int s = 1; s < 128; s <<= 1) {
    const int add = (t >= s) ? tmp[t - s] : 0;
    __syncthreads();
    tmp[t] += add;
    __syncthreads();
  }
  if (t < NB) bsum[r * NB + t] = (t == 0) ? 0 : tmp[t - 1];
}

__global__ __launch_bounds__(256) void scanC_kernel(
    const int* __restrict__ bsum, int* __restrict__ offs) {
  const int r = blockIdx.y, bx = blockIdx.x, t = threadIdx.x;
  const int i = bx * 256 + t;
  if (i < NN) offs[r * (NN + 1) + i + 1] += bsum[r * NB + bx];
  if (i == 0) offs[r * (NN + 1)] = 0;
}

__global__ __launch_bounds__(256) void fill_kernel(
    const int* __restrict__ esrc, const int* __restrict__ etgt,
    const int* __restrict__ offs, int* __restrict__ cursor,
    int* __restrict__ csr) {
  const int e = blockIdx.x * 256 + threadIdx.x;
  const int r = blockIdx.y;
  if (e < EE) {
    const int s = esrc[(size_t)r * EE + e];
    const int pos = offs[r * (NN + 1) + s] + atomicAdd(&cursor[r * NN + s], 1);
    csr[(size_t)r * EE + pos] = etgt[(size_t)r * EE + e];
  }
}

// ---------------------------------------------------------------------------
// Y-GEMM (R4 structure): grid (313, 20): r = by/5, tile = by%5.
// tile<4: Y[r][n][256] cols tile*64..+63. tile==4: ab[r][n][8] (alpha|beta).
__global__ __launch_bounds__(256) void ygemm_kernel(
    const ushort* __restrict__ xbf, const ushort* __restrict__ mT_l,
    ushort* __restrict__ Y, ushort* __restrict__ ab) {
  const int t = threadIdx.x;
  const int w = t >> 6, l = t & 63;
  const int hi = l >> 4, lo = l & 15;
  const int m0 = blockIdx.x * 64;
  const int r = blockIdx.y / 5;
  const int tile = blockIdx.y % 5;
  const ushort* wT = mT_l + (size_t)r * 17408;  // [272][64]
  const int row = min(m0 + w * 16 + lo, NN - 1);
  const ushort* arow = xbf + (size_t)row * 64 + hi * 8;
  const bf16x8 a0 = *(const bf16x8*)(arow);
  const bf16x8 a1 = *(const bf16x8*)(arow + 32);
  if (tile < 4) {
    const int n0 = tile * 64;
    f32x4 acc[4];
#pragma unroll
    for (int nt = 0; nt < 4; ++nt) {
      const ushort* brow = wT + (size_t)(n0 + nt * 16 + lo) * 64 + hi * 8;
      const bf16x8 b0 = *(const bf16x8*)(brow);
      const bf16x8 b1 = *(const bf16x8*)(brow + 32);
      f32x4 z = {0.f, 0.f, 0.f, 0.f};
      z = __builtin_amdgcn_mfma_f32_16x16x32_bf16(a0, b0, z, 0, 0, 0);
      z = __builtin_amdgcn_mfma_f32_16x16x32_bf16(a1, b1, z, 0, 0, 0);
      acc[nt] = z;
    }
    __shared__ ushort cs[64][72];
#pragma unroll
    for (int nt = 0; nt < 4; ++nt) {
#pragma unroll
      for (int i = 0; i < 4; ++i) {
        cs[w * 16 + hi * 4 + i][nt * 16 + lo] = f2bf(acc[nt][i]);
      }
    }
    __syncthreads();
    const int rr = t >> 2, c0 = (t & 3) * 16;
    const int gm = m0 + rr;
    if (gm < NN) {
      const uint4 v0 = *(const uint4*)&cs[rr][c0];
      const uint4 v1 = *(const uint4*)&cs[rr][c0 + 8];
      ushort* dst = Y + ((size_t)r * NN + gm) * 256 + n0 + c0;
      *(uint4*)(dst) = v0;
      *(uint4*)(dst + 8) = v1;
    }
  } else {
    // alpha/beta tile: cols 256..271 of mT (8 real)
    const ushort* brow = wT + (size_t)(256 + lo) * 64 + hi * 8;
    const bf16x8 b0 = *(const bf16x8*)(brow);
    const bf16x8 b1 = *(const bf16x8*)(brow + 32);
    f32x4 z = {0.f, 0.f, 0.f, 0.f};
    z = __builtin_amdgcn_mfma_f32_16x16x32_bf16(a0, b0, z, 0, 0, 0);
    z = __builtin_amdgcn_mfma_f32_16x16x32_bf16(a1, b1, z, 0, 0, 0);
#pragma unroll
    for (int i = 0; i < 4; ++i) {
      const int gm = m0 + w * 16 + hi * 4 + i;
      if (gm < NN && lo < 8) {
        ab[((size_t)r * NN + gm) * 8 + lo] = f2bf(z[i]);
      }
    }
  }
}

// ---------------------------------------------------------------------------
// Attention: one block per node; wave = relation; 16 lanes per head x 4 dims.
// score = (Y[src].x[tgt] + alpha[src] + beta[tgt] + gamma) * 0.125*nsi*sw.
// Single online-softmax stream in exp2 domain; 1-deep gather prefetch;
// readfirstlane(csr) moves per-edge address math to SALU.
__global__ __launch_bounds__(256) void attn_kernel(
    const ushort* __restrict__ xbf, const ushort* __restrict__ Y,
    const ushort* __restrict__ ab, const int* __restrict__ offs4,
    const int* __restrict__ csr4, const float* __restrict__ nsi,
    const float* __restrict__ sw_l, const float* __restrict__ gam_l,
    ushort* __restrict__ attr) {
  const int n = blockIdx.x;
  const int t = threadIdx.x;
  const int r = t >> 6, l = t & 63;
  const int h = l >> 4, lo = l & 15;
  const int* offs = offs4 + r * (NN + 1);
  const int* csr = csr4 + (size_t)r * EE;
  const ushort4 yu = *(const ushort4*)(Y + ((size_t)r * NN + n) * 256 + l * 4);
  const float y0 = bf2f(yu.x), y1 = bf2f(yu.y), y2 = bf2f(yu.z),
              y3 = bf2f(yu.w);
  const float alpha = bf2f(ab[((size_t)r * NN + n) * 8 + h]) + gam_l[r * 4 + h];
  // c2 = 0.125 * log2(e) * nsi * sw  (exp2-domain softmax: exact same result)
  const float c2 = 0.18033688f * nsi[n] * sw_l[h * RR + r];
  const int s0 = offs[n], e0 = offs[n + 1];
  float m2 = -INFINITY, den = 0.f;
  float o0 = 0.f, o1 = 0.f, o2 = 0.f, o3 = 0.f;
  if (s0 < e0) {
    int tg = __builtin_amdgcn_readfirstlane(csr[s0]);
    ushort4 xu = *(const ushort4*)(xbf + (size_t)tg * 64 + lo * 4);
    ushort beu = ab[((size_t)r * NN + tg) * 8 + 4 + h];
    for (int i = s0; i < e0; ++i) {
      const ushort4 cx = xu;
      const ushort cb = beu;
      if (i + 1 < e0) {  // prefetch next edge (wave-uniform branch)
        tg = __builtin_amdgcn_readfirstlane(csr[i + 1]);
        xu = *(const ushort4*)(xbf + (size_t)tg * 64 + lo * 4);
        beu = ab[((size_t)r * NN + tg) * 8 + 4 + h];
      }
      const float x0 = bf2f(cx.x), x1 = bf2f(cx.y), x2 = bf2f(cx.z),
                  x3 = bf2f(cx.w);
      float d = y0 * x0;
      d = fmaf(y1, x1, d);
      d = fmaf(y2, x2, d);
      d = fmaf(y3, x3, d);
#pragma unroll
      for (int dd = 1; dd < 16; dd <<= 1) d += __shfl_xor(d, dd);
      const float sc = (d + alpha + bf2f(cb)) * c2;
      const float mn = fmaxf(m2, sc);
      const float esc = __builtin_amdgcn_exp2f(m2 - mn);
      const float ew = __builtin_amdgcn_exp2f(sc - mn);
      den = fmaf(den, esc, ew);
      o0 = fmaf(ew, x0, o0 * esc);
      o1 = fmaf(ew, x1, o1 * esc);
      o2 = fmaf(ew, x2, o2 * esc);
      o3 = fmaf(ew, x3, o3 * esc);
      m2 = mn;
    }
  }
  const float inv = 1.f / (den + 1e-10f);
  ushort4 ou;
  ou.x = f2bf(o0 * inv);
  ou.y = f2bf(o1 * inv);
  ou.z = f2bf(o2 * inv);
  ou.w = f2bf(o3 * inv);
  *(ushort4*)(attr + (size_t)n * 1024 + r * 256 + l * 4) = ou;
}

// ---------------------------------------------------------------------------
// Projection via fused G (K=1024) + masked bv-consts + bias + residual + LN.
// grid (N/16), block 256 = 4 waves each own a 256-K-slice; LDS reduce; wave 0
// does the epilogue.
__global__ __launch_bounds__(256) void proj_ln_kernel(
    const ushort* __restrict__ attr, const ushort* __restrict__ gT,
    const float* __restrict__ xin, const float* __restrict__ bp,
    const float* __restrict__ g, const float* __restrict__ b,
    const int* __restrict__ offs4, const float* __restrict__ cvec_l,
    float* __restrict__ xout, ushort* __restrict__ xbf_out) {
  __shared__ float red[4][64][20];
  const int t = threadIdx.x;
  const int w = t >> 6, l = t & 63;
  const int hi = l >> 4, lo = l & 15;
  const int m0 = blockIdx.x * 16;
  const ushort* arow = attr + (size_t)(m0 + lo) * 1024 + w * 256 + hi * 8;
  f32x4 acc[4] = {{0.f, 0.f, 0.f, 0.f},
                  {0.f, 0.f, 0.f, 0.f},
                  {0.f, 0.f, 0.f, 0.f},
                  {0.f, 0.f, 0.f, 0.f}};
#pragma unroll
  for (int ks = 0; ks < 8; ++ks) {
    const bf16x8 a = *(const bf16x8*)(arow + ks * 32);
#pragma unroll
    for (int nt = 0; nt < 4; ++nt) {
      const bf16x8 bb = *(const bf16x8*)(gT + (size_t)(nt * 16 + lo) * 1024 +
                                         w * 256 + ks * 32 + hi * 8);
      acc[nt] = __builtin_amdgcn_mfma_f32_16x16x32_bf16(a, bb, acc[nt], 0, 0, 0);
    }
  }
#pragma unroll
  for (int nt = 0; nt < 4; ++nt) *(f32x4*)&red[w][l][nt * 4] = acc[nt];
  __syncthreads();
  if (w == 0) {
    f32x4 fin[4];
#pragma unroll
    for (int nt = 0; nt < 4; ++nt) {
      f32x4 s = *(const f32x4*)&red[0][l][nt * 4];
      s += *(const f32x4*)&red[1][l][nt * 4];
      s += *(const f32x4*)&red[2][l][nt * 4];
      s += *(const f32x4*)&red[3][l][nt * 4];
      fin[nt] = s;
    }
#pragma unroll
    for (int i = 0; i < 4; ++i) {
      const int gr = m0 + hi * 4 + i;
      float fl[4];
#pragma unroll
      for (int r = 0; r < 4; ++r) {
        fl[r] = (offs4[r * (NN + 1) + gr + 1] > offs4[r * (NN + 1) + gr])
                    ? 1.f
                    : 0.f;
      }
      float y[4];
      float s = 0.f, s2 = 0.f;
#pragma unroll
      for (int nt = 0; nt < 4; ++nt) {
        const int col = nt * 16 + lo;
        float extra = fl[0] * cvec_l[col] + fl[1] * cvec_l[64 + col] +
                      fl[2] * cvec_l[128 + col] + fl[3] * cvec_l[192 + col];
        const float yv =
            fin[nt][i] + bp[col] + extra + xin[(size_t)gr * 64 + col];
        y[nt] = yv;
        s += yv;
        s2 = fmaf(yv, yv, s2);
      }
#pragma unroll
      for (int d = 1; d < 16; d <<= 1) {
        s += __shfl_xor(s, d);
        s2 += __shfl_xor(s2, d);
      }
      const float mu = s * (1.f / 64.f);
      const float var = s2 * (1.f / 64.f) - mu * mu;
      const float rstd = rsqrtf(var + 1e-5f);
#pragma unroll
      for (int nt = 0; nt < 4; ++nt) {
        const int col = nt * 16 + lo;
        const float xo = (y[nt] - mu) * rstd * g[col] + b[col];
        xout[(size_t)gr * 64 + col] = xo;
        if (xbf_out) xbf_out[(size_t)gr * 64 + col] = f2bf(xo);
      }
    }
  }
}

// ---------------------------------------------------------------------------
extern "C" void kernel_launch(void* const* d_in, const int* in_sizes, int n_in,
                              void* d_out, int out_size, void* d_ws,
                              size_t ws_size, hipStream_t stream) {
  const float* feat = (const float*)d_in[1];
  const float* bet = (const float*)d_in[2];
  const float* clo = (const float*)d_in[3];
  const float* nsi = (const float*)d_in[4];
  const int* esrc = (const int*)d_in[5];
  const int* etgt = (const int*)d_in[6];
  const float* Wf = (const float*)d_in[7];
  const float* bf = (const float*)d_in[8];
  const float* Wc = (const float*)d_in[9];
  const float* bc = (const float*)d_in[10];
  const float* Wq = (const float*)d_in[11];
  const float* bq = (const float*)d_in[12];
  const float* Wk = (const float*)d_in[13];
  const float* bk = (const float*)d_in[14];
  const float* Wv = (const float*)d_in[15];
  const float* bv = (const float*)d_in[16];
  const float* Wp = (const float*)d_in[17];
  const float* bp = (const float*)d_in[18];
  const float* sw = (const float*)d_in[19];
  const float* lng = (const float*)d_in[20];
  const float* lnb = (const float*)d_in[21];
  float* out = (float*)d_out;

  char* base = (char*)d_ws;
  size_t off = 0;
  auto alloc = [&](size_t bytes) {
    void* p = base + off;
    off += (bytes + 255) & ~(size_t)255;
    return p;
  };
  float* xa = (float*)alloc((size_t)NN * DD * 4);        // 5.12 MB
  float* xb = (float*)alloc((size_t)NN * DD * 4);        // 5.12 MB
  ushort* xbf = (ushort*)alloc((size_t)NN * DD * 2);     // 2.56 MB
  ushort* Yb = (ushort*)alloc((size_t)RR * NN * 256 * 2);  // 40.96 MB
  ushort* ab = (ushort*)alloc((size_t)RR * NN * 8 * 2);    // 1.28 MB
  ushort* attr = (ushort*)alloc((size_t)NN * 1024 * 2);    // 40.96 MB
  ushort* mT = (ushort*)alloc((size_t)LL * RR * 272 * 64 * 2);  // 557 KB
  ushort* gT = (ushort*)alloc((size_t)LL * 64 * 1024 * 2);      // 262 KB
  float* cvec = (float*)alloc((size_t)LL * RR * 64 * 4);        // 2 KB
  float* gam = (float*)alloc((size_t)LL * RR * HH * 4);         // 128 B
  int* counts = (int*)alloc((size_t)RR * NN * 4);
  int* offsb = (int*)alloc((size_t)RR * (NN + 1) * 4);
  int* bsum = (int*)alloc((size_t)RR * NB * 4);
  int* csr = (int*)alloc((size_t)RR * EE * 4);
  (void)ws_size;

  // ---- CSR build ----
  hipMemsetAsync(counts, 0, (size_t)RR * NN * 4, stream);
  {
    dim3 gg((EE + 255) / 256, RR);
    hipLaunchKernelGGL(hist_kernel, gg, dim3(256), 0, stream, esrc, counts);
  }
  {
    dim3 gg(NB, RR);
    hipLaunchKernelGGL(scanA_kernel, gg, dim3(256), 0, stream, counts, offsb,
                       bsum);
    hipLaunchKernelGGL(scanB_kernel, dim3(RR), dim3(128), 0, stream, bsum);
    hipLaunchKernelGGL(scanC_kernel, gg, dim3(256), 0, stream, bsum, offsb);
  }
  hipMemsetAsync(counts, 0, (size_t)RR * NN * 4, stream);  // reuse as cursor
  {
    dim3 gg((EE + 255) / 256, RR);
    hipLaunchKernelGGL(fill_kernel, gg, dim3(256), 0, stream, esrc, etgt, offsb,
                       counts, csr);
  }

  // ---- fused-weight precompute + encoder ----
  hipLaunchKernelGGL(prep_kernel, dim3(1059), dim3(256), 0, stream, Wq, bq, Wk,
                     bk, Wv, bv, Wp, mT, gT, cvec, gam);
  hipLaunchKernelGGL(encoder_kernel, dim3((NN + 3) / 4), dim3(256), 0, stream,
                     feat, bet, clo, Wf, bf, Wc, bc, xa, xbf);

  const int gm = (NN + 63) / 64;  // 313
  for (int l = 0; l < LL; ++l) {
    const float* xin = (l == 0) ? xa : xb;
    float* xout = (l == LL - 1) ? out : xb;
    ushort* xbf_next = (l == LL - 1) ? (ushort*)nullptr : xbf;
    hipLaunchKernelGGL(ygemm_kernel, dim3(gm, 20), dim3(256), 0, stream, xbf,
                       mT + (size_t)l * RR * 17408, Yb, ab);
    hipLaunchKernelGGL(attn_kernel, dim3(NN), dim3(256), 0, stream, xbf, Yb,
                       ab, offsb, csr, nsi, sw + l * HH * RR, gam + l * 16,
                       attr);
    hipLaunchKernelGGL(proj_ln_kernel, dim3(NN / 16), dim3(256), 0, stream,
                       attr, gT + (size_t)l * 65536, xin, bp + l * 64,
                       lng + l * 64, lnb + l * 64, offsb, cvec + l * 256, xout,
                       xbf_next);
  }
}

// Round 8
// 328.030 us; speedup vs baseline: 1.3506x; 1.0312x over previous
//
#include <hip/hip_runtime.h>
#include <math.h>

#define NN 20000
#define EE 100000
#define RR 4
#define HH 4
#define DD 64
#define FF 128
#define LL 2
#define NB 79  // scan blocks per relation: ceil(20000/256)

typedef __attribute__((ext_vector_type(8))) short bf16x8;
typedef __attribute__((ext_vector_type(4))) float f32x4;

__device__ __forceinline__ ushort f2bf(float f) {
  uint u = __float_as_uint(f);
  u += 0x7FFFu + ((u >> 16) & 1u);
  return (ushort)(u >> 16);
}
__device__ __forceinline__ float bf2f(ushort h) {
  return __uint_as_float((uint)h << 16);
}

// ---------------------------------------------------------------------------
// Encoder: x = feat@Wf + bf + cen@Wc + bc ; writes fp32 x and bf16 xbf
__global__ __launch_bounds__(256) void encoder_kernel(
    const float* __restrict__ feat, const float* __restrict__ bet,
    const float* __restrict__ clo, const float* __restrict__ Wf,
    const float* __restrict__ bf, const float* __restrict__ Wc,
    const float* __restrict__ bc, float* __restrict__ x,
    ushort* __restrict__ xbf) {
  __shared__ float fs[4][FF];
  const int t = threadIdx.x;
  const int n0 = blockIdx.x * 4;
  for (int idx = t; idx < 4 * FF; idx += 256) {
    const int rr = idx >> 7, cc = idx & 127;
    const int n = n0 + rr;
    fs[rr][cc] = (n < NN) ? feat[(size_t)n * FF + cc] : 0.f;
  }
  __syncthreads();
  const int g = t >> 6, d = t & 63;
  const int n = n0 + g;
  if (n >= NN) return;
  float acc = bf[d] + bc[d] + bet[n] * Wc[d] + clo[n] * Wc[DD + d];
#pragma unroll 8
  for (int f = 0; f < FF; ++f) acc = fmaf(fs[g][f], Wf[f * DD + d], acc);
  x[(size_t)n * DD + d] = acc;
  xbf[(size_t)n * DD + d] = f2bf(acc);
}

// ---------------------------------------------------------------------------
// Precompute fused weights (exact, fp32 accum):
//  mT[l][r][272][64] bf16: cols 0..255: M_h[i][j] = sum_d Wq[i][h64+d]Wk[j][h64+d]
//                          cols 256..259: walpha_h[i] = sum_d Wq[i][h64+d] bk[h64+d]
//                          cols 260..263: wbeta_h[i]  = sum_d Wk[i][h64+d] bq[h64+d]
//  gT[l][64][1024] bf16:  gT[j][r*256+h*64+v] = sum_d Wv[v][h64+d] Wp[r256+h64+d][j]
//  cvec[l][r][64] f32:    sum_idx bv[idx] Wp[r*256+idx][j]   (deg>0 const)
//  gam[l][r][h] f32:      bq_h . bk_h
__global__ __launch_bounds__(256) void prep_kernel(
    const float* __restrict__ Wq, const float* __restrict__ bq,
    const float* __restrict__ Wk, const float* __restrict__ bk,
    const float* __restrict__ Wv, const float* __restrict__ bv,
    const float* __restrict__ Wp, ushort* __restrict__ mT,
    ushort* __restrict__ gT, float* __restrict__ cvec,
    float* __restrict__ gam) {
  const int idx = blockIdx.x * 256 + threadIdx.x;
  const int R1 = LL * RR * 272 * 64;  // 139264
  const int R2 = LL * 64 * 1024;      // 131072
  if (idx < R1) {
    const int lr = idx / (272 * 64);
    const int rem = idx % (272 * 64);
    const int col = rem >> 6, i = rem & 63;
    const float* wq = Wq + (size_t)lr * 64 * 256;
    const float* wk = Wk + (size_t)lr * 64 * 256;
    float v = 0.f;
    if (col < 256) {
      const int h = col >> 6, j = col & 63;
      const float* qa = wq + (size_t)i * 256 + h * 64;
      const float* kb = wk + (size_t)j * 256 + h * 64;
#pragma unroll 8
      for (int d = 0; d < 64; ++d) v = fmaf(qa[d], kb[d], v);
    } else if (col < 260) {
      const int h = col - 256;
      const float* qa = wq + (size_t)i * 256 + h * 64;
      const float* bb = bk + lr * 256 + h * 64;
#pragma unroll 8
      for (int d = 0; d < 64; ++d) v = fmaf(qa[d], bb[d], v);
    } else if (col < 264) {
      const int h = col - 260;
      const float* ka = wk + (size_t)i * 256 + h * 64;
      const float* bb = bq + lr * 256 + h * 64;
#pragma unroll 8
      for (int d = 0; d < 64; ++d) v = fmaf(ka[d], bb[d], v);
    }
    mT[idx] = f2bf(v);
  } else if (idx < R1 + R2) {
    const int id = idx - R1;  // = l*65536 + j*1024 + k
    const int lj = id >> 10;
    const int k = id & 1023;
    const int l = lj >> 6, j = lj & 63;
    const int r = k >> 8, h = (k >> 6) & 3, v_ = k & 63;
    const float* wv = Wv + (size_t)(l * RR + r) * 64 * 256 + (size_t)v_ * 256 + h * 64;
    const float* wp = Wp + (size_t)l * 65536 + (size_t)(r * 256 + h * 64) * 64 + j;
    float s = 0.f;
#pragma unroll 8
    for (int d = 0; d < 64; ++d) s = fmaf(wv[d], wp[d * 64], s);
    gT[id] = f2bf(s);
  } else if (idx < R1 + R2 + 512) {
    const int id = idx - R1 - R2;  // = l*256 + r*64 + j
    const int l = id >> 8, rj = id & 255;
    const int r = rj >> 6, j = rj & 63;
    const float* bb = bv + (l * RR + r) * 256;
    const float* wp = Wp + (size_t)l * 65536 + (size_t)(r * 256) * 64 + j;
    float s = 0.f;
    for (int q2 = 0; q2 < 256; ++q2) s = fmaf(bb[q2], wp[q2 * 64], s);
    cvec[id] = s;
  } else if (idx < R1 + R2 + 512 + 32) {
    const int id = idx - R1 - R2 - 512;  // = l*16 + r*4 + h (lr*4+h)
    const int lr = id >> 2, h = id & 3;
    const float* a = bq + lr * 256 + h * 64;
    const float* b2 = bk + lr * 256 + h * 64;
    float s = 0.f;
    for (int d = 0; d < 64; ++d) s = fmaf(a[d], b2[d], s);
    gam[id] = s;
  }
}

// ---------------------------------------------------------------------------
// CSR build
__global__ __launch_bounds__(256) void hist_kernel(
    const int* __restrict__ esrc, int* __restrict__ counts) {
  const int e = blockIdx.x * 256 + threadIdx.x;
  const int r = blockIdx.y;
  if (e < EE) atomicAdd(&counts[r * NN + esrc[(size_t)r * EE + e]], 1);
}

__global__ __launch_bounds__(256) void scanA_kernel(
    const int* __restrict__ counts, int* __restrict__ offs,
    int* __restrict__ bsum) {
  __shared__ int tmp[256];
  const int r = blockIdx.y, bx = blockIdx.x, t = threadIdx.x;
  const int i = bx * 256 + t;
  tmp[t] = (i < NN) ? counts[r * NN + i] : 0;
  __syncthreads();
#pragma unroll
  for (int s = 1; s < 256; s <<= 1) {
    const int add = (t >= s) ? tmp[t - s] : 0;
    __syncthreads();
    tmp[t] += add;
    __syncthreads();
  }
  if (i < NN) offs[r * (NN + 1) + i + 1] = tmp[t];
  if (t == 255) bsum[r * NB + bx] = tmp[255];
}

__global__ __launch_bounds__(128) void scanB_kernel(int* __restrict__ bsum) {
  __shared__ int tmp[128];
  const int r = blockIdx.x, t = threadIdx.x;
  tmp[t] = (t < NB) ? bsum[r * NB + t] : 0;
  __syncthreads();
#pragma unroll
  for (int s = 1; s < 128; s <<= 1) {
    const int add = (t >= s) ? tmp[t - s] : 0;
    __syncthreads();
    tmp[t] += add;
    __syncthreads();
  }
  if (t < NB) bsum[r * NB + t] = (t == 0) ? 0 : tmp[t - 1];
}

__global__ __launch_bounds__(256) void scanC_kernel(
    const int* __restrict__ bsum, int* __restrict__ offs) {
  const int r = blockIdx.y, bx = blockIdx.x, t = threadIdx.x;
  const int i = bx * 256 + t;
  if (i < NN) offs[r * (NN + 1) + i + 1] += bsum[r * NB + bx];
  if (i == 0) offs[r * (NN + 1)] = 0;
}

__global__ __launch_bounds__(256) void fill_kernel(
    const int* __restrict__ esrc, const int* __restrict__ etgt,
    const int* __restrict__ offs, int* __restrict__ cursor,
    int* __restrict__ csr) {
  const int e = blockIdx.x * 256 + threadIdx.x;
  const int r = blockIdx.y;
  if (e < EE) {
    const int s = esrc[(size_t)r * EE + e];
    const int pos = offs[r * (NN + 1) + s] + atomicAdd(&cursor[r * NN + s], 1);
    csr[(size_t)r * EE + pos] = etgt[(size_t)r * EE + e];
  }
}

// ---------------------------------------------------------------------------
// Y-GEMM (R4 structure): grid (313, 20): r = by/5, tile = by%5.
// tile<4: Y[r][n][256] cols tile*64..+63. tile==4: ab[r][n][8] (alpha|beta).
__global__ __launch_bounds__(256) void ygemm_kernel(
    const ushort* __restrict__ xbf, const ushort* __restrict__ mT_l,
    ushort* __restrict__ Y, ushort* __restrict__ ab) {
  const int t = threadIdx.x;
  const int w = t >> 6, l = t & 63;
  const int hi = l >> 4, lo = l & 15;
  const int m0 = blockIdx.x * 64;
  const int r = blockIdx.y / 5;
  const int tile = blockIdx.y % 5;
  const ushort* wT = mT_l + (size_t)r * 17408;  // [272][64]
  const int row = min(m0 + w * 16 + lo, NN - 1);
  const ushort* arow = xbf + (size_t)row * 64 + hi * 8;
  const bf16x8 a0 = *(const bf16x8*)(arow);
  const bf16x8 a1 = *(const bf16x8*)(arow + 32);
  if (tile < 4) {
    const int n0 = tile * 64;
    f32x4 acc[4];
#pragma unroll
    for (int nt = 0; nt < 4; ++nt) {
      const ushort* brow = wT + (size_t)(n0 + nt * 16 + lo) * 64 + hi * 8;
      const bf16x8 b0 = *(const bf16x8*)(brow);
      const bf16x8 b1 = *(const bf16x8*)(brow + 32);
      f32x4 z = {0.f, 0.f, 0.f, 0.f};
      z = __builtin_amdgcn_mfma_f32_16x16x32_bf16(a0, b0, z, 0, 0, 0);
      z = __builtin_amdgcn_mfma_f32_16x16x32_bf16(a1, b1, z, 0, 0, 0);
      acc[nt] = z;
    }
    __shared__ ushort cs[64][72];
#pragma unroll
    for (int nt = 0; nt < 4; ++nt) {
#pragma unroll
      for (int i = 0; i < 4; ++i) {
        cs[w * 16 + hi * 4 + i][nt * 16 + lo] = f2bf(acc[nt][i]);
      }
    }
    __syncthreads();
    const int rr = t >> 2, c0 = (t & 3) * 16;
    const int gm = m0 + rr;
    if (gm < NN) {
      const uint4 v0 = *(const uint4*)&cs[rr][c0];
      const uint4 v1 = *(const uint4*)&cs[rr][c0 + 8];
      ushort* dst = Y + ((size_t)r * NN + gm) * 256 + n0 + c0;
      *(uint4*)(dst) = v0;
      *(uint4*)(dst + 8) = v1;
    }
  } else {
    // alpha/beta tile: cols 256..271 of mT (8 real)
    const ushort* brow = wT + (size_t)(256 + lo) * 64 + hi * 8;
    const bf16x8 b0 = *(const bf16x8*)(brow);
    const bf16x8 b1 = *(const bf16x8*)(brow + 32);
    f32x4 z = {0.f, 0.f, 0.f, 0.f};
    z = __builtin_amdgcn_mfma_f32_16x16x32_bf16(a0, b0, z, 0, 0, 0);
    z = __builtin_amdgcn_mfma_f32_16x16x32_bf16(a1, b1, z, 0, 0, 0);
#pragma unroll
    for (int i = 0; i < 4; ++i) {
      const int gm = m0 + w * 16 + hi * 4 + i;
      if (gm < NN && lo < 8) {
        ab[((size_t)r * NN + gm) * 8 + lo] = f2bf(z[i]);
      }
    }
  }
}

// ---------------------------------------------------------------------------
// Attention: one block per node; wave = relation; 16 lanes per head x 4 dims.
// score = (Y[src].x[tgt] + alpha[src] + beta[tgt] + gamma) * 0.125*nsi*sw.
// MAX-FREE softmax in exp2 domain (mathematically identical; scores here are
// |sc| < ~1 << 127 so fp32 exp2 cannot overflow): den += 2^sc, o += 2^sc * x.
// 1-deep gather prefetch; readfirstlane(csr) keeps edge addressing on SALU.
__global__ __launch_bounds__(256) void attn_kernel(
    const ushort* __restrict__ xbf, const ushort* __restrict__ Y,
    const ushort* __restrict__ ab, const int* __restrict__ offs4,
    const int* __restrict__ csr4, const float* __restrict__ nsi,
    const float* __restrict__ sw_l, const float* __restrict__ gam_l,
    ushort* __restrict__ attr) {
  const int n = blockIdx.x;
  const int t = threadIdx.x;
  const int r = t >> 6, l = t & 63;
  const int h = l >> 4, lo = l & 15;
  const int* offs = offs4 + r * (NN + 1);
  const int* csr = csr4 + (size_t)r * EE;
  const ushort4 yu = *(const ushort4*)(Y + ((size_t)r * NN + n) * 256 + l * 4);
  const float y0 = bf2f(yu.x), y1 = bf2f(yu.y), y2 = bf2f(yu.z),
              y3 = bf2f(yu.w);
  // c2 = 0.125 * log2(e) * nsi * sw ; ac2 = (alpha + gamma) * c2
  const float c2 = 0.18033688f * nsi[n] * sw_l[h * RR + r];
  const float ac2 =
      (bf2f(ab[((size_t)r * NN + n) * 8 + h]) + gam_l[r * 4 + h]) * c2;
  const int s0 = offs[n], e0 = offs[n + 1];
  float den = 0.f;
  float o0 = 0.f, o1 = 0.f, o2 = 0.f, o3 = 0.f;
  if (s0 < e0) {
    int tg = __builtin_amdgcn_readfirstlane(csr[s0]);
    ushort4 xu = *(const ushort4*)(xbf + (size_t)tg * 64 + lo * 4);
    ushort beu = ab[((size_t)r * NN + tg) * 8 + 4 + h];
    for (int i = s0; i < e0; ++i) {
      const ushort4 cx = xu;
      const ushort cb = beu;
      if (i + 1 < e0) {  // prefetch next edge (wave-uniform branch)
        tg = __builtin_amdgcn_readfirstlane(csr[i + 1]);
        xu = *(const ushort4*)(xbf + (size_t)tg * 64 + lo * 4);
        beu = ab[((size_t)r * NN + tg) * 8 + 4 + h];
      }
      const float x0 = bf2f(cx.x), x1 = bf2f(cx.y), x2 = bf2f(cx.z),
                  x3 = bf2f(cx.w);
      float d = y0 * x0;
      d = fmaf(y1, x1, d);
      d = fmaf(y2, x2, d);
      d = fmaf(y3, x3, d);
#pragma unroll
      for (int dd = 1; dd < 16; dd <<= 1) d += __shfl_xor(d, dd);
      const float pre = fmaf(bf2f(cb), c2, ac2);
      const float sc = fmaf(d, c2, pre);
      const float ew = __builtin_amdgcn_exp2f(sc);
      den += ew;
      o0 = fmaf(ew, x0, o0);
      o1 = fmaf(ew, x1, o1);
      o2 = fmaf(ew, x2, o2);
      o3 = fmaf(ew, x3, o3);
    }
  }
  const float inv = 1.f / (den + 1e-10f);
  ushort4 ou;
  ou.x = f2bf(o0 * inv);
  ou.y = f2bf(o1 * inv);
  ou.z = f2bf(o2 * inv);
  ou.w = f2bf(o3 * inv);
  *(ushort4*)(attr + (size_t)n * 1024 + r * 256 + l * 4) = ou;
}

// ---------------------------------------------------------------------------
// Projection via fused G (K=1024) + masked bv-consts + bias + residual + LN.
// grid (N/16), block 256 = 4 waves each own a 256-K-slice; LDS reduce; wave 0
// does the epilogue.
__global__ __launch_bounds__(256) void proj_ln_kernel(
    const ushort* __restrict__ attr, const ushort* __restrict__ gT,
    const float* __restrict__ xin, const float* __restrict__ bp,
    const float* __restrict__ g, const float* __restrict__ b,
    const int* __restrict__ offs4, const float* __restrict__ cvec_l,
    float* __restrict__ xout, ushort* __restrict__ xbf_out) {
  __shared__ float red[4][64][20];
  const int t = threadIdx.x;
  const int w = t >> 6, l = t & 63;
  const int hi = l >> 4, lo = l & 15;
  const int m0 = blockIdx.x * 16;
  const ushort* arow = attr + (size_t)(m0 + lo) * 1024 + w * 256 + hi * 8;
  f32x4 acc[4] = {{0.f, 0.f, 0.f, 0.f},
                  {0.f, 0.f, 0.f, 0.f},
                  {0.f, 0.f, 0.f, 0.f},
                  {0.f, 0.f, 0.f, 0.f}};
#pragma unroll
  for (int ks = 0; ks < 8; ++ks) {
    const bf16x8 a = *(const bf16x8*)(arow + ks * 32);
#pragma unroll
    for (int nt = 0; nt < 4; ++nt) {
      const bf16x8 bb = *(const bf16x8*)(gT + (size_t)(nt * 16 + lo) * 1024 +
                                         w * 256 + ks * 32 + hi * 8);
      acc[nt] = __builtin_amdgcn_mfma_f32_16x16x32_bf16(a, bb, acc[nt], 0, 0, 0);
    }
  }
#pragma unroll
  for (int nt = 0; nt < 4; ++nt) *(f32x4*)&red[w][l][nt * 4] = acc[nt];
  __syncthreads();
  if (w == 0) {
    f32x4 fin[4];
#pragma unroll
    for (int nt = 0; nt < 4; ++nt) {
      f32x4 s = *(const f32x4*)&red[0][l][nt * 4];
      s += *(const f32x4*)&red[1][l][nt * 4];
      s += *(const f32x4*)&red[2][l][nt * 4];
      s += *(const f32x4*)&red[3][l][nt * 4];
      fin[nt] = s;
    }
#pragma unroll
    for (int i = 0; i < 4; ++i) {
      const int gr = m0 + hi * 4 + i;
      float fl[4];
#pragma unroll
      for (int r = 0; r < 4; ++r) {
        fl[r] = (offs4[r * (NN + 1) + gr + 1] > offs4[r * (NN + 1) + gr])
                    ? 1.f
                    : 0.f;
      }
      float y[4];
      float s = 0.f, s2 = 0.f;
#pragma unroll
      for (int nt = 0; nt < 4; ++nt) {
        const int col = nt * 16 + lo;
        float extra = fl[0] * cvec_l[col] + fl[1] * cvec_l[64 + col] +
                      fl[2] * cvec_l[128 + col] + fl[3] * cvec_l[192 + col];
        const float yv =
            fin[nt][i] + bp[col] + extra + xin[(size_t)gr * 64 + col];
        y[nt] = yv;
        s += yv;
        s2 = fmaf(yv, yv, s2);
      }
#pragma unroll
      for (int d = 1; d < 16; d <<= 1) {
        s += __shfl_xor(s, d);
        s2 += __shfl_xor(s2, d);
      }
      const float mu = s * (1.f / 64.f);
      const float var = s2 * (1.f / 64.f) - mu * mu;
      const float rstd = rsqrtf(var + 1e-5f);
#pragma unroll
      for (int nt = 0; nt < 4; ++nt) {
        const int col = nt * 16 + lo;
        const float xo = (y[nt] - mu) * rstd * g[col] + b[col];
        xout[(size_t)gr * 64 + col] = xo;
        if (xbf_out) xbf_out[(size_t)gr * 64 + col] = f2bf(xo);
      }
    }
  }
}

// ---------------------------------------------------------------------------
extern "C" void kernel_launch(void* const* d_in, const int* in_sizes, int n_in,
                              void* d_out, int out_size, void* d_ws,
                              size_t ws_size, hipStream_t stream) {
  const float* feat = (const float*)d_in[1];
  const float* bet = (const float*)d_in[2];
  const float* clo = (const float*)d_in[3];
  const float* nsi = (const float*)d_in[4];
  const int* esrc = (const int*)d_in[5];
  const int* etgt = (const int*)d_in[6];
  const float* Wf = (const float*)d_in[7];
  const float* bf = (const float*)d_in[8];
  const float* Wc = (const float*)d_in[9];
  const float* bc = (const float*)d_in[10];
  const float* Wq = (const float*)d_in[11];
  const float* bq = (const float*)d_in[12];
  const float* Wk = (const float*)d_in[13];
  const float* bk = (const float*)d_in[14];
  const float* Wv = (const float*)d_in[15];
  const float* bv = (const float*)d_in[16];
  const float* Wp = (const float*)d_in[17];
  const float* bp = (const float*)d_in[18];
  const float* sw = (const float*)d_in[19];
  const float* lng = (const float*)d_in[20];
  const float* lnb = (const float*)d_in[21];
  float* out = (float*)d_out;

  char* base = (char*)d_ws;
  size_t off = 0;
  auto alloc = [&](size_t bytes) {
    void* p = base + off;
    off += (bytes + 255) & ~(size_t)255;
    return p;
  };
  float* xa = (float*)alloc((size_t)NN * DD * 4);        // 5.12 MB
  float* xb = (float*)alloc((size_t)NN * DD * 4);        // 5.12 MB
  ushort* xbf = (ushort*)alloc((size_t)NN * DD * 2);     // 2.56 MB
  ushort* Yb = (ushort*)alloc((size_t)RR * NN * 256 * 2);  // 40.96 MB
  ushort* ab = (ushort*)alloc((size_t)RR * NN * 8 * 2);    // 1.28 MB
  ushort* attr = (ushort*)alloc((size_t)NN * 1024 * 2);    // 40.96 MB
  ushort* mT = (ushort*)alloc((size_t)LL * RR * 272 * 64 * 2);  // 557 KB
  ushort* gT = (ushort*)alloc((size_t)LL * 64 * 1024 * 2);      // 262 KB
  float* cvec = (float*)alloc((size_t)LL * RR * 64 * 4);        // 2 KB
  float* gam = (float*)alloc((size_t)LL * RR * HH * 4);         // 128 B
  int* counts = (int*)alloc((size_t)RR * NN * 4);
  int* offsb = (int*)alloc((size_t)RR * (NN + 1) * 4);
  int* bsum = (int*)alloc((size_t)RR * NB * 4);
  int* csr = (int*)alloc((size_t)RR * EE * 4);
  (void)ws_size;

  // ---- CSR build ----
  hipMemsetAsync(counts, 0, (size_t)RR * NN * 4, stream);
  {
    dim3 gg((EE + 255) / 256, RR);
    hipLaunchKernelGGL(hist_kernel, gg, dim3(256), 0, stream, esrc, counts);
  }
  {
    dim3 gg(NB, RR);
    hipLaunchKernelGGL(scanA_kernel, gg, dim3(256), 0, stream, counts, offsb,
                       bsum);
    hipLaunchKernelGGL(scanB_kernel, dim3(RR), dim3(128), 0, stream, bsum);
    hipLaunchKernelGGL(scanC_kernel, gg, dim3(256), 0, stream, bsum, offsb);
  }
  hipMemsetAsync(counts, 0, (size_t)RR * NN * 4, stream);  // reuse as cursor
  {
    dim3 gg((EE + 255) / 256, RR);
    hipLaunchKernelGGL(fill_kernel, gg, dim3(256), 0, stream, esrc, etgt, offsb,
                       counts, csr);
  }

  // ---- fused-weight precompute + encoder ----
  hipLaunchKernelGGL(prep_kernel, dim3(1059), dim3(256), 0, stream, Wq, bq, Wk,
                     bk, Wv, bv, Wp, mT, gT, cvec, gam);
  hipLaunchKernelGGL(encoder_kernel, dim3((NN + 3) / 4), dim3(256), 0, stream,
                     feat, bet, clo, Wf, bf, Wc, bc, xa, xbf);

  const int gm = (NN + 63) / 64;  // 313
  for (int l = 0; l < LL; ++l) {
    const float* xin = (l == 0) ? xa : xb;
    float* xout = (l == LL - 1) ? out : xb;
    ushort* xbf_next = (l == LL - 1) ? (ushort*)nullptr : xbf;
    hipLaunchKernelGGL(ygemm_kernel, dim3(gm, 20), dim3(256), 0, stream, xbf,
                       mT + (size_t)l * RR * 17408, Yb, ab);
    hipLaunchKernelGGL(attn_kernel, dim3(NN), dim3(256), 0, stream, xbf, Yb,
                       ab, offsb, csr, nsi, sw + l * HH * RR, gam + l * 16,
                       attr);
    hipLaunchKernelGGL(proj_ln_kernel, dim3(NN / 16), dim3(256), 0, stream,
                       attr, gT + (size_t)l * 65536, xin, bp + l * 64,
                       lng + l * 64, lnb + l * 64, offsb, cvec + l * 256, xout,
                       xbf_next);
  }
}

// Round 9
// 314.593 us; speedup vs baseline: 1.4083x; 1.0427x over previous
//
#include <hip/hip_runtime.h>
#include <math.h>

#define NN 20000
#define EE 100000
#define RR 4
#define HH 4
#define DD 64
#define FF 128
#define LL 2

typedef __attribute__((ext_vector_type(8))) short bf16x8;
typedef __attribute__((ext_vector_type(4))) float f32x4;

__device__ __forceinline__ ushort f2bf(float f) {
  uint u = __float_as_uint(f);
  u += 0x7FFFu + ((u >> 16) & 1u);
  return (ushort)(u >> 16);
}
__device__ __forceinline__ float bf2f(ushort h) {
  return __uint_as_float((uint)h << 16);
}

// ---------------------------------------------------------------------------
// Fused encoder + weight-prep. Blocks [0,5000): encoder; [5000,6059): prep.
// Encoder: x = feat@Wf + bf + cen@Wc + bc ; writes fp32 x and bf16 xbf.
// Prep (exact, fp32 accum):
//  mT[l][r][272][64] bf16: cols 0..255: M_h[i][j]=sum_d Wq[i][h64+d]Wk[j][h64+d]
//                          cols 256..259: walpha_h[i]; cols 260..263: wbeta_h[i]
//  gT[l][64][1024] bf16 ; cvec[l][r][64] f32 ; gam[l][r][h] f32
__global__ __launch_bounds__(256) void enc_prep_kernel(
    const float* __restrict__ feat, const float* __restrict__ bet,
    const float* __restrict__ clo, const float* __restrict__ Wf,
    const float* __restrict__ bf, const float* __restrict__ Wc,
    const float* __restrict__ bc, float* __restrict__ x,
    ushort* __restrict__ xbf, const float* __restrict__ Wq,
    const float* __restrict__ bq, const float* __restrict__ Wk,
    const float* __restrict__ bk, const float* __restrict__ Wv,
    const float* __restrict__ bv, const float* __restrict__ Wp,
    ushort* __restrict__ mT, ushort* __restrict__ gT, float* __restrict__ cvec,
    float* __restrict__ gam) {
  const int t = threadIdx.x;
  if (blockIdx.x < 5000) {
    __shared__ float fs[4][FF];
    const int n0 = blockIdx.x * 4;
    for (int idx = t; idx < 4 * FF; idx += 256) {
      const int rr = idx >> 7, cc = idx & 127;
      const int n = n0 + rr;
      fs[rr][cc] = (n < NN) ? feat[(size_t)n * FF + cc] : 0.f;
    }
    __syncthreads();
    const int g = t >> 6, d = t & 63;
    const int n = n0 + g;
    if (n >= NN) return;
    float acc = bf[d] + bc[d] + bet[n] * Wc[d] + clo[n] * Wc[DD + d];
#pragma unroll 8
    for (int f = 0; f < FF; ++f) acc = fmaf(fs[g][f], Wf[f * DD + d], acc);
    x[(size_t)n * DD + d] = acc;
    xbf[(size_t)n * DD + d] = f2bf(acc);
    return;
  }
  const int idx = (blockIdx.x - 5000) * 256 + t;
  const int R1 = LL * RR * 272 * 64;  // 139264
  const int R2 = LL * 64 * 1024;      // 131072
  if (idx < R1) {
    const int lr = idx / (272 * 64);
    const int rem = idx % (272 * 64);
    const int col = rem >> 6, i = rem & 63;
    const float* wq = Wq + (size_t)lr * 64 * 256;
    const float* wk = Wk + (size_t)lr * 64 * 256;
    float v = 0.f;
    if (col < 256) {
      const int h = col >> 6, j = col & 63;
      const float* qa = wq + (size_t)i * 256 + h * 64;
      const float* kb = wk + (size_t)j * 256 + h * 64;
#pragma unroll 8
      for (int d = 0; d < 64; ++d) v = fmaf(qa[d], kb[d], v);
    } else if (col < 260) {
      const int h = col - 256;
      const float* qa = wq + (size_t)i * 256 + h * 64;
      const float* bb = bk + lr * 256 + h * 64;
#pragma unroll 8
      for (int d = 0; d < 64; ++d) v = fmaf(qa[d], bb[d], v);
    } else if (col < 264) {
      const int h = col - 260;
      const float* ka = wk + (size_t)i * 256 + h * 64;
      const float* bb = bq + lr * 256 + h * 64;
#pragma unroll 8
      for (int d = 0; d < 64; ++d) v = fmaf(ka[d], bb[d], v);
    }
    mT[idx] = f2bf(v);
  } else if (idx < R1 + R2) {
    const int id = idx - R1;  // = l*65536 + j*1024 + k
    const int lj = id >> 10;
    const int k = id & 1023;
    const int l = lj >> 6, j = lj & 63;
    const int r = k >> 8, h = (k >> 6) & 3, v_ = k & 63;
    const float* wv =
        Wv + (size_t)(l * RR + r) * 64 * 256 + (size_t)v_ * 256 + h * 64;
    const float* wp =
        Wp + (size_t)l * 65536 + (size_t)(r * 256 + h * 64) * 64 + j;
    float s = 0.f;
#pragma unroll 8
    for (int d = 0; d < 64; ++d) s = fmaf(wv[d], wp[d * 64], s);
    gT[id] = f2bf(s);
  } else if (idx < R1 + R2 + 512) {
    const int id = idx - R1 - R2;  // = l*256 + r*64 + j
    const int l = id >> 8, rj = id & 255;
    const int r = rj >> 6, j = rj & 63;
    const float* bb = bv + (l * RR + r) * 256;
    const float* wp = Wp + (size_t)l * 65536 + (size_t)(r * 256) * 64 + j;
    float s = 0.f;
    for (int q2 = 0; q2 < 256; ++q2) s = fmaf(bb[q2], wp[q2 * 64], s);
    cvec[id] = s;
  } else if (idx < R1 + R2 + 512 + 32) {
    const int id = idx - R1 - R2 - 512;  // = lr*4 + h
    const int lr = id >> 2, h = id & 3;
    const float* a = bq + lr * 256 + h * 64;
    const float* b2 = bk + lr * 256 + h * 64;
    float s = 0.f;
    for (int d = 0; d < 64; ++d) s = fmaf(a[d], b2[d], s);
    gam[id] = s;
  }
}

// ---------------------------------------------------------------------------
// CSR build
__global__ __launch_bounds__(256) void hist_kernel(
    const int* __restrict__ esrc, int* __restrict__ counts) {
  const int e = blockIdx.x * 256 + threadIdx.x;
  const int r = blockIdx.y;
  if (e < EE) atomicAdd(&counts[r * NN + esrc[(size_t)r * EE + e]], 1);
}

// Single-kernel exclusive scan: 1 block/relation, 1024 threads x 20 elems.
__global__ __launch_bounds__(1024) void scan_kernel(
    const int* __restrict__ counts, int* __restrict__ offs) {
  __shared__ int ts[1024];
  const int r = blockIdx.x, t = threadIdx.x;
  const int base = t * 20;
  int loc[20];
  int run = 0;
#pragma unroll
  for (int k = 0; k < 20; ++k) {
    const int i = base + k;
    const int v = (i < NN) ? counts[r * NN + i] : 0;
    run += v;
    loc[k] = run;
  }
  ts[t] = run;
  __syncthreads();
#pragma unroll
  for (int s = 1; s < 1024; s <<= 1) {
    const int add = (t >= s) ? ts[t - s] : 0;
    __syncthreads();
    ts[t] += add;
    __syncthreads();
  }
  const int prev = (t == 0) ? 0 : ts[t - 1];
#pragma unroll
  for (int k = 0; k < 20; ++k) {
    const int i = base + k;
    if (i < NN) offs[r * (NN + 1) + i + 1] = prev + loc[k];
  }
  if (t == 0) offs[r * (NN + 1)] = 0;
}

__global__ __launch_bounds__(256) void fill_kernel(
    const int* __restrict__ esrc, const int* __restrict__ etgt,
    const int* __restrict__ offs, int* __restrict__ cursor,
    int* __restrict__ csr) {
  const int e = blockIdx.x * 256 + threadIdx.x;
  const int r = blockIdx.y;
  if (e < EE) {
    const int s = esrc[(size_t)r * EE + e];
    const int pos = offs[r * (NN + 1) + s] + atomicAdd(&cursor[r * NN + s], 1);
    csr[(size_t)r * EE + pos] = etgt[(size_t)r * EE + e];
  }
}

// ---------------------------------------------------------------------------
// Y-GEMM (R4 structure): grid (313, 20): r = by/5, tile = by%5.
// tile<4: Y[r][n][256] cols tile*64..+63. tile==4: ab[r][n][8] (alpha|beta).
__global__ __launch_bounds__(256) void ygemm_kernel(
    const ushort* __restrict__ xbf, const ushort* __restrict__ mT_l,
    ushort* __restrict__ Y, ushort* __restrict__ ab) {
  const int t = threadIdx.x;
  const int w = t >> 6, l = t & 63;
  const int hi = l >> 4, lo = l & 15;
  const int m0 = blockIdx.x * 64;
  const int r = blockIdx.y / 5;
  const int tile = blockIdx.y % 5;
  const ushort* wT = mT_l + (size_t)r * 17408;  // [272][64]
  const int row = min(m0 + w * 16 + lo, NN - 1);
  const ushort* arow = xbf + (size_t)row * 64 + hi * 8;
  const bf16x8 a0 = *(const bf16x8*)(arow);
  const bf16x8 a1 = *(const bf16x8*)(arow + 32);
  if (tile < 4) {
    const int n0 = tile * 64;
    f32x4 acc[4];
#pragma unroll
    for (int nt = 0; nt < 4; ++nt) {
      const ushort* brow = wT + (size_t)(n0 + nt * 16 + lo) * 64 + hi * 8;
      const bf16x8 b0 = *(const bf16x8*)(brow);
      const bf16x8 b1 = *(const bf16x8*)(brow + 32);
      f32x4 z = {0.f, 0.f, 0.f, 0.f};
      z = __builtin_amdgcn_mfma_f32_16x16x32_bf16(a0, b0, z, 0, 0, 0);
      z = __builtin_amdgcn_mfma_f32_16x16x32_bf16(a1, b1, z, 0, 0, 0);
      acc[nt] = z;
    }
    __shared__ ushort cs[64][72];
#pragma unroll
    for (int nt = 0; nt < 4; ++nt) {
#pragma unroll
      for (int i = 0; i < 4; ++i) {
        cs[w * 16 + hi * 4 + i][nt * 16 + lo] = f2bf(acc[nt][i]);
      }
    }
    __syncthreads();
    const int rr = t >> 2, c0 = (t & 3) * 16;
    const int gm = m0 + rr;
    if (gm < NN) {
      const uint4 v0 = *(const uint4*)&cs[rr][c0];
      const uint4 v1 = *(const uint4*)&cs[rr][c0 + 8];
      ushort* dst = Y + ((size_t)r * NN + gm) * 256 + n0 + c0;
      *(uint4*)(dst) = v0;
      *(uint4*)(dst + 8) = v1;
    }
  } else {
    // alpha/beta tile: cols 256..271 of mT (8 real)
    const ushort* brow = wT + (size_t)(256 + lo) * 64 + hi * 8;
    const bf16x8 b0 = *(const bf16x8*)(brow);
    const bf16x8 b1 = *(const bf16x8*)(brow + 32);
    f32x4 z = {0.f, 0.f, 0.f, 0.f};
    z = __builtin_amdgcn_mfma_f32_16x16x32_bf16(a0, b0, z, 0, 0, 0);
    z = __builtin_amdgcn_mfma_f32_16x16x32_bf16(a1, b1, z, 0, 0, 0);
#pragma unroll
    for (int i = 0; i < 4; ++i) {
      const int gm = m0 + w * 16 + hi * 4 + i;
      if (gm < NN && lo < 8) {
        ab[((size_t)r * NN + gm) * 8 + lo] = f2bf(z[i]);
      }
    }
  }
}

// ---------------------------------------------------------------------------
// Attention: one block per node; wave = relation; 16 lanes per head x 4 dims.
// score = (Y[src].x[tgt] + alpha[src] + beta[tgt] + gamma) * 0.125*nsi*sw.
// MAX-FREE softmax in exp2 domain; DUAL independent edge streams (exactly
// mergeable by addition since no running max); readfirstlane(csr) keeps edge
// addressing on SALU.
__global__ __launch_bounds__(256) void attn_kernel(
    const ushort* __restrict__ xbf, const ushort* __restrict__ Y,
    const ushort* __restrict__ ab, const int* __restrict__ offs4,
    const int* __restrict__ csr4, const float* __restrict__ nsi,
    const float* __restrict__ sw_l, const float* __restrict__ gam_l,
    ushort* __restrict__ attr) {
  const int n = blockIdx.x;
  const int t = threadIdx.x;
  const int r = t >> 6, l = t & 63;
  const int h = l >> 4, lo = l & 15;
  const int* offs = offs4 + r * (NN + 1);
  const int* csr = csr4 + (size_t)r * EE;
  const ushort4 yu = *(const ushort4*)(Y + ((size_t)r * NN + n) * 256 + l * 4);
  const float y0 = bf2f(yu.x), y1 = bf2f(yu.y), y2 = bf2f(yu.z),
              y3 = bf2f(yu.w);
  // c2 = 0.125 * log2(e) * nsi * sw ; ac2 = (alpha + gamma) * c2
  const float c2 = 0.18033688f * nsi[n] * sw_l[h * RR + r];
  const float ac2 =
      (bf2f(ab[((size_t)r * NN + n) * 8 + h]) + gam_l[r * 4 + h]) * c2;
  const int s0 = offs[n], e0 = offs[n + 1];
  float denA = 0.f, oA0 = 0.f, oA1 = 0.f, oA2 = 0.f, oA3 = 0.f;
  float denB = 0.f, oB0 = 0.f, oB1 = 0.f, oB2 = 0.f, oB3 = 0.f;
  int i = s0;
  for (; i + 1 < e0; i += 2) {
    const int tgA = __builtin_amdgcn_readfirstlane(csr[i]);
    const int tgB = __builtin_amdgcn_readfirstlane(csr[i + 1]);
    const ushort4 cxA = *(const ushort4*)(xbf + (size_t)tgA * 64 + lo * 4);
    const ushort4 cxB = *(const ushort4*)(xbf + (size_t)tgB * 64 + lo * 4);
    const float bA = bf2f(ab[((size_t)r * NN + tgA) * 8 + 4 + h]);
    const float bB = bf2f(ab[((size_t)r * NN + tgB) * 8 + 4 + h]);
    const float xA0 = bf2f(cxA.x), xA1 = bf2f(cxA.y), xA2 = bf2f(cxA.z),
                xA3 = bf2f(cxA.w);
    const float xB0 = bf2f(cxB.x), xB1 = bf2f(cxB.y), xB2 = bf2f(cxB.z),
                xB3 = bf2f(cxB.w);
    float dA = y0 * xA0;
    float dB = y0 * xB0;
    dA = fmaf(y1, xA1, dA);
    dB = fmaf(y1, xB1, dB);
    dA = fmaf(y2, xA2, dA);
    dB = fmaf(y2, xB2, dB);
    dA = fmaf(y3, xA3, dA);
    dB = fmaf(y3, xB3, dB);
#pragma unroll
    for (int dd = 1; dd < 16; dd <<= 1) {
      dA += __shfl_xor(dA, dd);
      dB += __shfl_xor(dB, dd);
    }
    const float scA = fmaf(dA, c2, fmaf(bA, c2, ac2));
    const float scB = fmaf(dB, c2, fmaf(bB, c2, ac2));
    const float ewA = __builtin_amdgcn_exp2f(scA);
    const float ewB = __builtin_amdgcn_exp2f(scB);
    denA += ewA;
    denB += ewB;
    oA0 = fmaf(ewA, xA0, oA0);
    oB0 = fmaf(ewB, xB0, oB0);
    oA1 = fmaf(ewA, xA1, oA1);
    oB1 = fmaf(ewB, xB1, oB1);
    oA2 = fmaf(ewA, xA2, oA2);
    oB2 = fmaf(ewB, xB2, oB2);
    oA3 = fmaf(ewA, xA3, oA3);
    oB3 = fmaf(ewB, xB3, oB3);
  }
  if (i < e0) {  // odd tail -> stream A
    const int tg = __builtin_amdgcn_readfirstlane(csr[i]);
    const ushort4 cx = *(const ushort4*)(xbf + (size_t)tg * 64 + lo * 4);
    const float bb = bf2f(ab[((size_t)r * NN + tg) * 8 + 4 + h]);
    const float x0 = bf2f(cx.x), x1 = bf2f(cx.y), x2 = bf2f(cx.z),
                x3 = bf2f(cx.w);
    float d = y0 * x0;
    d = fmaf(y1, x1, d);
    d = fmaf(y2, x2, d);
    d = fmaf(y3, x3, d);
#pragma unroll
    for (int dd = 1; dd < 16; dd <<= 1) d += __shfl_xor(d, dd);
    const float sc = fmaf(d, c2, fmaf(bb, c2, ac2));
    const float ew = __builtin_amdgcn_exp2f(sc);
    denA += ew;
    oA0 = fmaf(ew, x0, oA0);
    oA1 = fmaf(ew, x1, oA1);
    oA2 = fmaf(ew, x2, oA2);
    oA3 = fmaf(ew, x3, oA3);
  }
  const float inv = 1.f / (denA + denB + 1e-10f);
  ushort4 ou;
  ou.x = f2bf((oA0 + oB0) * inv);
  ou.y = f2bf((oA1 + oB1) * inv);
  ou.z = f2bf((oA2 + oB2) * inv);
  ou.w = f2bf((oA3 + oB3) * inv);
  *(ushort4*)(attr + (size_t)n * 1024 + r * 256 + l * 4) = ou;
}

// ---------------------------------------------------------------------------
// Projection via fused G (K=1024) + masked bv-consts + bias + residual + LN.
// grid (N/16), block 256 = 4 waves each own a 256-K-slice; LDS reduce; wave 0
// does the epilogue.
__global__ __launch_bounds__(256) void proj_ln_kernel(
    const ushort* __restrict__ attr, const ushort* __restrict__ gT,
    const float* __restrict__ xin, const float* __restrict__ bp,
    const float* __restrict__ g, const float* __restrict__ b,
    const int* __restrict__ offs4, const float* __restrict__ cvec_l,
    float* __restrict__ xout, ushort* __restrict__ xbf_out) {
  __shared__ float red[4][64][20];
  const int t = threadIdx.x;
  const int w = t >> 6, l = t & 63;
  const int hi = l >> 4, lo = l & 15;
  const int m0 = blockIdx.x * 16;
  const ushort* arow = attr + (size_t)(m0 + lo) * 1024 + w * 256 + hi * 8;
  f32x4 acc[4] = {{0.f, 0.f, 0.f, 0.f},
                  {0.f, 0.f, 0.f, 0.f},
                  {0.f, 0.f, 0.f, 0.f},
                  {0.f, 0.f, 0.f, 0.f}};
#pragma unroll
  for (int ks = 0; ks < 8; ++ks) {
    const bf16x8 a = *(const bf16x8*)(arow + ks * 32);
#pragma unroll
    for (int nt = 0; nt < 4; ++nt) {
      const bf16x8 bb = *(const bf16x8*)(gT + (size_t)(nt * 16 + lo) * 1024 +
                                         w * 256 + ks * 32 + hi * 8);
      acc[nt] = __builtin_amdgcn_mfma_f32_16x16x32_bf16(a, bb, acc[nt], 0, 0, 0);
    }
  }
#pragma unroll
  for (int nt = 0; nt < 4; ++nt) *(f32x4*)&red[w][l][nt * 4] = acc[nt];
  __syncthreads();
  if (w == 0) {
    f32x4 fin[4];
#pragma unroll
    for (int nt = 0; nt < 4; ++nt) {
      f32x4 s = *(const f32x4*)&red[0][l][nt * 4];
      s += *(const f32x4*)&red[1][l][nt * 4];
      s += *(const f32x4*)&red[2][l][nt * 4];
      s += *(const f32x4*)&red[3][l][nt * 4];
      fin[nt] = s;
    }
#pragma unroll
    for (int i = 0; i < 4; ++i) {
      const int gr = m0 + hi * 4 + i;
      float fl[4];
#pragma unroll
      for (int r = 0; r < 4; ++r) {
        fl[r] = (offs4[r * (NN + 1) + gr + 1] > offs4[r * (NN + 1) + gr])
                    ? 1.f
                    : 0.f;
      }
      float y[4];
      float s = 0.f, s2 = 0.f;
#pragma unroll
      for (int nt = 0; nt < 4; ++nt) {
        const int col = nt * 16 + lo;
        float extra = fl[0] * cvec_l[col] + fl[1] * cvec_l[64 + col] +
                      fl[2] * cvec_l[128 + col] + fl[3] * cvec_l[192 + col];
        const float yv =
            fin[nt][i] + bp[col] + extra + xin[(size_t)gr * 64 + col];
        y[nt] = yv;
        s += yv;
        s2 = fmaf(yv, yv, s2);
      }
#pragma unroll
      for (int d = 1; d < 16; d <<= 1) {
        s += __shfl_xor(s, d);
        s2 += __shfl_xor(s2, d);
      }
      const float mu = s * (1.f / 64.f);
      const float var = s2 * (1.f / 64.f) - mu * mu;
      const float rstd = rsqrtf(var + 1e-5f);
#pragma unroll
      for (int nt = 0; nt < 4; ++nt) {
        const int col = nt * 16 + lo;
        const float xo = (y[nt] - mu) * rstd * g[col] + b[col];
        xout[(size_t)gr * 64 + col] = xo;
        if (xbf_out) xbf_out[(size_t)gr * 64 + col] = f2bf(xo);
      }
    }
  }
}

// ---------------------------------------------------------------------------
extern "C" void kernel_launch(void* const* d_in, const int* in_sizes, int n_in,
                              void* d_out, int out_size, void* d_ws,
                              size_t ws_size, hipStream_t stream) {
  const float* feat = (const float*)d_in[1];
  const float* bet = (const float*)d_in[2];
  const float* clo = (const float*)d_in[3];
  const float* nsi = (const float*)d_in[4];
  const int* esrc = (const int*)d_in[5];
  const int* etgt = (const int*)d_in[6];
  const float* Wf = (const float*)d_in[7];
  const float* bf = (const float*)d_in[8];
  const float* Wc = (const float*)d_in[9];
  const float* bc = (const float*)d_in[10];
  const float* Wq = (const float*)d_in[11];
  const float* bq = (const float*)d_in[12];
  const float* Wk = (const float*)d_in[13];
  const float* bk = (const float*)d_in[14];
  const float* Wv = (const float*)d_in[15];
  const float* bv = (const float*)d_in[16];
  const float* Wp = (const float*)d_in[17];
  const float* bp = (const float*)d_in[18];
  const float* sw = (const float*)d_in[19];
  const float* lng = (const float*)d_in[20];
  const float* lnb = (const float*)d_in[21];
  float* out = (float*)d_out;

  char* base = (char*)d_ws;
  size_t off = 0;
  auto alloc = [&](size_t bytes) {
    void* p = base + off;
    off += (bytes + 255) & ~(size_t)255;
    return p;
  };
  float* xa = (float*)alloc((size_t)NN * DD * 4);        // 5.12 MB
  float* xb = (float*)alloc((size_t)NN * DD * 4);        // 5.12 MB
  ushort* xbf = (ushort*)alloc((size_t)NN * DD * 2);     // 2.56 MB
  ushort* Yb = (ushort*)alloc((size_t)RR * NN * 256 * 2);  // 40.96 MB
  ushort* ab = (ushort*)alloc((size_t)RR * NN * 8 * 2);    // 1.28 MB
  ushort* attr = (ushort*)alloc((size_t)NN * 1024 * 2);    // 40.96 MB
  ushort* mT = (ushort*)alloc((size_t)LL * RR * 272 * 64 * 2);  // 557 KB
  ushort* gT = (ushort*)alloc((size_t)LL * 64 * 1024 * 2);      // 262 KB
  float* cvec = (float*)alloc((size_t)LL * RR * 64 * 4);        // 2 KB
  float* gam = (float*)alloc((size_t)LL * RR * HH * 4);         // 128 B
  int* counts = (int*)alloc((size_t)RR * NN * 4);
  int* offsb = (int*)alloc((size_t)RR * (NN + 1) * 4);
  int* csr = (int*)alloc((size_t)RR * EE * 4);
  (void)ws_size;

  // ---- CSR build ----
  hipMemsetAsync(counts, 0, (size_t)RR * NN * 4, stream);
  {
    dim3 gg((EE + 255) / 256, RR);
    hipLaunchKernelGGL(hist_kernel, gg, dim3(256), 0, stream, esrc, counts);
  }
  hipLaunchKernelGGL(scan_kernel, dim3(RR), dim3(1024), 0, stream, counts,
                     offsb);
  hipMemsetAsync(counts, 0, (size_t)RR * NN * 4, stream);  // reuse as cursor
  {
    dim3 gg((EE + 255) / 256, RR);
    hipLaunchKernelGGL(fill_kernel, gg, dim3(256), 0, stream, esrc, etgt, offsb,
                       counts, csr);
  }

  // ---- fused encoder + weight prep ----
  hipLaunchKernelGGL(enc_prep_kernel, dim3(6059), dim3(256), 0, stream, feat,
                     bet, clo, Wf, bf, Wc, bc, xa, xbf, Wq, bq, Wk, bk, Wv, bv,
                     Wp, mT, gT, cvec, gam);

  const int gm = (NN + 63) / 64;  // 313
  for (int l = 0; l < LL; ++l) {
    const float* xin = (l == 0) ? xa : xb;
    float* xout = (l == LL - 1) ? out : xb;
    ushort* xbf_next = (l == LL - 1) ? (ushort*)nullptr : xbf;
    hipLaunchKernelGGL(ygemm_kernel, dim3(gm, 20), dim3(256), 0, stream, xbf,
                       mT + (size_t)l * RR * 17408, Yb, ab);
    hipLaunchKernelGGL(attn_kernel, dim3(NN), dim3(256), 0, stream, xbf, Yb,
                       ab, offsb, csr, nsi, sw + l * HH * RR, gam + l * 16,
                       attr);
    hipLaunchKernelGGL(proj_ln_kernel, dim3(NN / 16), dim3(256), 0, stream,
                       attr, gT + (size_t)l * 65536, xin, bp + l * 64,
                       lng + l * 64, lnb + l * 64, offsb, cvec + l * 256, xout,
                       xbf_next);
  }
}